// Round 1
// baseline (290.762 us; speedup 1.0000x reference)
//
#include <hip/hip_runtime.h>
#include <hip/hip_bf16.h>

constexpr int NN = 256;
constexpr int HH = 128;
constexpr int GG = 512;   // 4H
constexpr int NP = NN * NN;

typedef __attribute__((ext_vector_type(8))) short short8;
typedef __attribute__((ext_vector_type(4))) float f32x4;

// static device scratch (d_ws size unknown; statics are safe & capture-friendly)
__device__ unsigned short g_xs[(size_t)NP * GG]; // bf16 bits: SE@Wxs+bs, upper-tri valid
__device__ float g_kterm[NP];
__device__ float g_yesw[NP];    // skip_dec with zeroed diagonal & lower-tri
__device__ float g_noskip[NN];  // diag(skip_dec)
__device__ float g_xg[NN * GG]; // node_emb@Wx + b
__device__ float g_hws[NN * HH * 4]; // h@Whs, layout [i][h][gate]
__device__ float g_c[NN * HH];
__device__ float g_h[NN * HH];
__device__ float g_sc[NN * HH];
__device__ float g_sh[NN * HH];
__device__ float g_ip[NN];
__device__ float g_nip[NN];

__device__ __forceinline__ unsigned short f2bf(float f) {
  unsigned int u = __float_as_uint(f);
  u = (u + 0x7fffu + ((u >> 16) & 1u)) >> 16;
  return (unsigned short)u;
}
__device__ __forceinline__ float bf2f(unsigned short s) {
  return __uint_as_float(((unsigned int)s) << 16);
}
__device__ __forceinline__ float frcp(float x) {
#if __has_builtin(__builtin_amdgcn_rcpf)
  return __builtin_amdgcn_rcpf(x);
#else
  return 1.0f / x;
#endif
}
__device__ __forceinline__ float sigm(float x) { return frcp(1.f + __expf(-x)); }
__device__ __forceinline__ float tanhfast(float x) { return 1.f - 2.f * frcp(__expf(2.f * x) + 1.f); }

// ---------------- init ----------------
__global__ void k_init() {
  int idx = blockIdx.x * blockDim.x + threadIdx.x; // 32768 threads
  g_sc[idx] = 0.f; g_sh[idx] = 0.f; g_c[idx] = 0.f; g_h[idx] = 0.f;
  if (idx < NN) { g_nip[idx] = 0.f; g_ip[idx] = (idx == 0) ? 1.f : 0.f; }
}

// ---------------- xg = node_emb @ Wx + b ----------------
__global__ __launch_bounds__(128) void k_xg(const float* __restrict__ NE,
                                            const float* __restrict__ Wx,
                                            const float* __restrict__ b) {
  const int i = blockIdx.x, t = threadIdx.x;
  __shared__ float ne[HH];
  ne[t] = NE[i * HH + t];
  __syncthreads();
  float a0 = b[t], a1 = b[128 + t], a2 = b[256 + t], a3 = b[384 + t];
  for (int k = 0; k < HH; ++k) {
    float x = ne[k];
    a0 = fmaf(x, Wx[k * GG + t], a0);
    a1 = fmaf(x, Wx[k * GG + 128 + t], a1);
    a2 = fmaf(x, Wx[k * GG + 256 + t], a2);
    a3 = fmaf(x, Wx[k * GG + 384 + t], a3);
  }
  g_xg[i * GG + t] = a0; g_xg[i * GG + 128 + t] = a1;
  g_xg[i * GG + 256 + t] = a2; g_xg[i * GG + 384 + t] = a3;
}

// ---------------- xs_gates = SE @ Wxs + bs (bf16 MFMA GEMM) ----------------
// tile: 128 pairs x 128 cols, K=128 fully staged. LDS: A 32KB + B^T 32KB = 64KB.
__global__ __launch_bounds__(256) void k_xsgates(const float* __restrict__ SE,
                                                 const float* __restrict__ Wxs,
                                                 const float* __restrict__ bs) {
  __shared__ char lds[65536];
  const int pb = blockIdx.x;  // 512 pair-tiles (all pairs of tile share i)
  const int cb = blockIdx.y;  // 4 col-tiles
  const int i_row = pb >> 1;
  const int jlo = (pb & 1) * 128;
  if (jlo + 127 <= i_row) return; // no j > i in this tile
  const int pairBase = pb * 128;
  const int colBase = cb * 128;
  const int tid = threadIdx.x;

  // A: [row][k] f32->bf16, swizzled (byte ^= (row&7)<<4)
  for (int cc = tid; cc < 2048; cc += 256) {
    int row = cc >> 4, kc = cc & 15;
    const float* src = SE + (size_t)(pairBase + row) * HH + kc * 8;
    float4 f0 = *(const float4*)(src);
    float4 f1 = *(const float4*)(src + 4);
    short8 v;
    v[0] = (short)f2bf(f0.x); v[1] = (short)f2bf(f0.y); v[2] = (short)f2bf(f0.z); v[3] = (short)f2bf(f0.w);
    v[4] = (short)f2bf(f1.x); v[5] = (short)f2bf(f1.y); v[6] = (short)f2bf(f1.z); v[7] = (short)f2bf(f1.w);
    *(short8*)(lds + row * 256 + ((kc * 16) ^ ((row & 7) << 4))) = v;
  }
  // B^T: [col][k]
  for (int e = tid; e < 16384; e += 256) {
    int k = e >> 7, c = e & 127;
    *(unsigned short*)(lds + 32768 + c * 256 + ((k * 2) ^ ((c & 7) << 4))) = f2bf(Wxs[k * GG + colBase + c]);
  }
  __syncthreads();

  const int wv = tid >> 6;
  const int l = tid & 63;
  const int l15 = l & 15, lg = l >> 4;
  f32x4 acc[2][8];
  for (int rt = 0; rt < 2; ++rt) for (int ct = 0; ct < 8; ++ct) acc[rt][ct] = (f32x4){0.f, 0.f, 0.f, 0.f};

  for (int ks = 0; ks < 4; ++ks) {
    const int kb = ks * 64 + lg * 16;
    short8 a[2], bfr[8];
#pragma unroll
    for (int rt = 0; rt < 2; ++rt) {
      int row = wv * 32 + rt * 16 + l15;
      a[rt] = *(const short8*)(lds + row * 256 + (kb ^ ((row & 7) << 4)));
    }
#pragma unroll
    for (int ct = 0; ct < 8; ++ct) {
      int col = ct * 16 + l15;
      bfr[ct] = *(const short8*)(lds + 32768 + col * 256 + (kb ^ ((col & 7) << 4)));
    }
#pragma unroll
    for (int rt = 0; rt < 2; ++rt)
#pragma unroll
      for (int ct = 0; ct < 8; ++ct)
        acc[rt][ct] = __builtin_amdgcn_mfma_f32_16x16x32_bf16(a[rt], bfr[ct], acc[rt][ct], 0, 0, 0);
  }

#pragma unroll
  for (int rt = 0; rt < 2; ++rt)
    for (int ct = 0; ct < 8; ++ct) {
      const int col = colBase + ct * 16 + l15;
      const float bsv = bs[col];
#pragma unroll
      for (int r = 0; r < 4; ++r) {
        int row = wv * 32 + rt * 16 + lg * 4 + r;
        int pair = pairBase + row;
        int jj = pair & 255, ii = pair >> 8;
        if (jj > ii) g_xs[(size_t)pair * GG + col] = f2bf(acc[rt][ct][r] + bsv);
      }
    }
}

// ---------------- kterm[i,j] = sum_h relu(SE@Wk + bk) * Wl[:H] ----------------
__global__ __launch_bounds__(256) void k_kterm(const float* __restrict__ SE,
                                               const float* __restrict__ Wk,
                                               const float* __restrict__ bk,
                                               const float* __restrict__ Wl) {
  __shared__ char lds[65536];
  const int pb = blockIdx.x; // 512
  const int i_row = pb >> 1;
  const int jlo = (pb & 1) * 128;
  if (jlo + 127 < i_row) return; // no j >= i
  const int pairBase = pb * 128;
  const int tid = threadIdx.x;

  for (int cc = tid; cc < 2048; cc += 256) {
    int row = cc >> 4, kc = cc & 15;
    const float* src = SE + (size_t)(pairBase + row) * HH + kc * 8;
    float4 f0 = *(const float4*)(src);
    float4 f1 = *(const float4*)(src + 4);
    short8 v;
    v[0] = (short)f2bf(f0.x); v[1] = (short)f2bf(f0.y); v[2] = (short)f2bf(f0.z); v[3] = (short)f2bf(f0.w);
    v[4] = (short)f2bf(f1.x); v[5] = (short)f2bf(f1.y); v[6] = (short)f2bf(f1.z); v[7] = (short)f2bf(f1.w);
    *(short8*)(lds + row * 256 + ((kc * 16) ^ ((row & 7) << 4))) = v;
  }
  for (int e = tid; e < 16384; e += 256) {
    int k = e >> 7, c = e & 127;
    *(unsigned short*)(lds + 32768 + c * 256 + ((k * 2) ^ ((c & 7) << 4))) = f2bf(Wk[k * HH + c]);
  }
  __syncthreads();

  const int wv = tid >> 6;
  const int l = tid & 63;
  const int l15 = l & 15, lg = l >> 4;
  f32x4 acc[2][8];
  for (int rt = 0; rt < 2; ++rt) for (int ct = 0; ct < 8; ++ct) acc[rt][ct] = (f32x4){0.f, 0.f, 0.f, 0.f};

  for (int ks = 0; ks < 4; ++ks) {
    const int kb = ks * 64 + lg * 16;
    short8 a[2], bfr[8];
#pragma unroll
    for (int rt = 0; rt < 2; ++rt) {
      int row = wv * 32 + rt * 16 + l15;
      a[rt] = *(const short8*)(lds + row * 256 + (kb ^ ((row & 7) << 4)));
    }
#pragma unroll
    for (int ct = 0; ct < 8; ++ct) {
      int col = ct * 16 + l15;
      bfr[ct] = *(const short8*)(lds + 32768 + col * 256 + (kb ^ ((col & 7) << 4)));
    }
#pragma unroll
    for (int rt = 0; rt < 2; ++rt)
#pragma unroll
      for (int ct = 0; ct < 8; ++ct)
        acc[rt][ct] = __builtin_amdgcn_mfma_f32_16x16x32_bf16(a[rt], bfr[ct], acc[rt][ct], 0, 0, 0);
  }

  for (int rt = 0; rt < 2; ++rt) {
#pragma unroll
    for (int r = 0; r < 4; ++r) {
      float s = 0.f;
#pragma unroll
      for (int ct = 0; ct < 8; ++ct) {
        int col = ct * 16 + l15;
        float x = acc[rt][ct][r] + bk[col];
        x = fmaxf(x, 0.f);
        s = fmaf(x, Wl[col], s);
      }
#pragma unroll
      for (int m = 1; m < 16; m <<= 1) s += __shfl_xor(s, m, 64);
      int row = wv * 32 + rt * 16 + lg * 4 + r;
      int pair = pairBase + row;
      int jj = pair & 255, ii = pair >> 8;
      if (l15 == 0 && jj >= ii) g_kterm[pair] = s;
    }
  }
}

// ---------------- masked row softmax -> yes_skip, no_skip ----------------
__global__ __launch_bounds__(256) void k_softmax() {
  const int i = blockIdx.x, j = threadIdx.x;
  __shared__ float sm[NN];
  float x = -1e30f;
  if (j >= i) x = g_kterm[i * NN + j];
  sm[j] = x;
  __syncthreads();
  for (int s = 128; s > 0; s >>= 1) { if (j < s) sm[j] = fmaxf(sm[j], sm[j + s]); __syncthreads(); }
  float mx = sm[0];
  __syncthreads();
  float e = (j >= i) ? __expf(x - mx) : 0.f;
  sm[j] = e;
  __syncthreads();
  for (int s = 128; s > 0; s >>= 1) { if (j < s) sm[j] += sm[j + s]; __syncthreads(); }
  float p = e * frcp(sm[0]);
  g_yesw[i * NN + j] = (j == i) ? 0.f : p;
  if (j == i) g_noskip[i] = p;
}

// ---------------- per-step: node LSTM, branch, scatter, h@Whs ----------------
__global__ __launch_bounds__(128) void k_node(const float* __restrict__ Wh,
                                              const float* __restrict__ Whs,
                                              const float* __restrict__ Wb,
                                              const float* __restrict__ bb,
                                              const int* __restrict__ tix,
                                              const int* __restrict__ fix) {
  const int i0 = blockIdx.x * 4;
  const int t = threadIdx.x;
  __shared__ float hsm[4][HH];
  __shared__ float red[2][4][2];
#pragma unroll
  for (int ii = 0; ii < 4; ++ii) hsm[ii][t] = g_h[(i0 + ii) * HH + t];
  __syncthreads();
  float aW[4][4], aS[4][4];
#pragma unroll
  for (int g = 0; g < 4; ++g)
#pragma unroll
    for (int ii = 0; ii < 4; ++ii) { aW[g][ii] = g_xg[(i0 + ii) * GG + g * 128 + t]; aS[g][ii] = 0.f; }
  for (int k = 0; k < HH; ++k) {
#pragma unroll
    for (int g = 0; g < 4; ++g) {
      float w1 = Wh[k * GG + g * 128 + t];
      float w2 = Whs[k * GG + g * 128 + t];
#pragma unroll
      for (int ii = 0; ii < 4; ++ii) {
        float hv = hsm[ii][k];
        aW[g][ii] = fmaf(hv, w1, aW[g][ii]);
        aS[g][ii] = fmaf(hv, w2, aS[g][ii]);
      }
    }
  }
#pragma unroll
  for (int ii = 0; ii < 4; ++ii) {
    float4 v = make_float4(aS[0][ii], aS[1][ii], aS[2][ii], aS[3][ii]);
    *(float4*)&g_hws[((size_t)(i0 + ii) * HH + t) * 4] = v;
  }
  float cp[4], hp[4];
#pragma unroll
  for (int ii = 0; ii < 4; ++ii) {
    float co = g_c[(i0 + ii) * HH + t];
    float c2 = sigm(aW[1][ii]) * co + sigm(aW[0][ii]) * tanhfast(aW[2][ii]);
    float h2 = sigm(aW[3][ii]) * tanhfast(c2);
    cp[ii] = c2; hp[ii] = h2;
  }
  float wb0 = Wb[2 * t], wb1 = Wb[2 * t + 1];
  float wb0h = Wb[2 * (128 + t)], wb1h = Wb[2 * (128 + t) + 1];
#pragma unroll
  for (int ii = 0; ii < 4; ++ii) {
    float q0 = cp[ii] * wb0 + hp[ii] * wb0h;
    float q1 = cp[ii] * wb1 + hp[ii] * wb1h;
#pragma unroll
    for (int m = 1; m < 64; m <<= 1) { q0 += __shfl_xor(q0, m, 64); q1 += __shfl_xor(q1, m, 64); }
    if ((t & 63) == 0) { red[t >> 6][ii][0] = q0; red[t >> 6][ii][1] = q1; }
  }
  __syncthreads();
#pragma unroll
  for (int ii = 0; ii < 4; ++ii) {
    float l0 = red[0][ii][0] + red[1][ii][0] + bb[0];
    float l1 = red[0][ii][1] + red[1][ii][1] + bb[1];
    float mm = fmaxf(l0, l1);
    float e0 = __expf(l0 - mm), e1 = __expf(l1 - mm);
    float inv = frcp(e0 + e1);
    float ipv = g_ip[i0 + ii] * g_noskip[i0 + ii];
    if (ipv != 0.f) {
      float pbt = ipv * e0 * inv, pbf = ipv * e1 * inv;
      int ti = tix[i0 + ii], fi = fix[i0 + ii];
      atomicAdd(&g_sc[ti * HH + t], cp[ii] * pbt);
      atomicAdd(&g_sh[ti * HH + t], hp[ii] * pbt);
      atomicAdd(&g_sc[fi * HH + t], cp[ii] * pbf);
      atomicAdd(&g_sh[fi * HH + t], hp[ii] * pbf);
      if (t == 0) { atomicAdd(&g_nip[ti], pbt); atomicAdd(&g_nip[fi], pbf); }
    }
  }
}

// ---------------- per-step: skip LSTM + weighted aggregation ----------------
__global__ __launch_bounds__(128) void k_skip() {
  const int j = blockIdx.x, ic = blockIdx.y, t = threadIdx.x;
  const int i0 = ic * 32;
  if (i0 >= j) return;
  const int i1 = (i0 + 32 < j) ? (i0 + 32) : j;
  float accC = 0.f, accH = 0.f, accW = 0.f;
  for (int i = i0; i < i1; ++i) {
    float wgt = g_ip[i] * g_yesw[i * NN + j];
    if (wgt == 0.f) continue;
    const unsigned short* gp = &g_xs[(size_t)(i * NN + j) * GG];
    float4 hw = *(const float4*)&g_hws[((size_t)i * HH + t) * 4];
    float xi = bf2f(gp[t]) + hw.x;
    float xf = bf2f(gp[128 + t]) + hw.y;
    float xg = bf2f(gp[256 + t]) + hw.z;
    float xo = bf2f(gp[384 + t]) + hw.w;
    float c2 = sigm(xf) * g_c[i * HH + t] + sigm(xi) * tanhfast(xg);
    float h2 = sigm(xo) * tanhfast(c2);
    accC = fmaf(wgt, c2, accC);
    accH = fmaf(wgt, h2, accH);
    accW += wgt;
  }
  if (accW != 0.f) {
    atomicAdd(&g_sc[j * HH + t], accC);
    atomicAdd(&g_sh[j * HH + t], accH);
    if (t == 0) atomicAdd(&g_nip[j], accW);
  }
}

// ---------------- per-step: finalize carry, zero accumulators ----------------
__global__ __launch_bounds__(128) void k_finish() {
  const int j = blockIdx.x, t = threadIdx.x;
  float nip = g_nip[j];
  float d = 1.f / (nip + 1e-7f);
  g_c[j * HH + t] = g_sc[j * HH + t] * d;
  g_h[j * HH + t] = g_sh[j * HH + t] * d;
  g_sc[j * HH + t] = 0.f;
  g_sh[j * HH + t] = 0.f;
  if (t == 0) { g_ip[j] = nip; g_nip[j] = 0.f; }
}

// ---------------- output: [c[exit], h[exit]] @ Wd + bd ----------------
__global__ __launch_bounds__(64) void k_out(const float* __restrict__ Wd,
                                            const float* __restrict__ bd,
                                            const int* __restrict__ ei,
                                            float* __restrict__ out) {
  const int v = threadIdx.x;
  const int e = ei[0];
  float s = bd[v];
  for (int h = 0; h < HH; ++h) {
    s = fmaf(g_c[e * HH + h], Wd[h * 64 + v], s);
    s = fmaf(g_h[e * HH + h], Wd[(128 + h) * 64 + v], s);
  }
  out[v] = s;
}

extern "C" void kernel_launch(void* const* d_in, const int* in_sizes, int n_in,
                              void* d_out, int out_size, void* d_ws, size_t ws_size,
                              hipStream_t stream) {
  const float* NE  = (const float*)d_in[0];
  const float* SE  = (const float*)d_in[1];
  const float* Wx  = (const float*)d_in[2];
  const float* Wh  = (const float*)d_in[3];
  const float* b   = (const float*)d_in[4];
  const float* Wxs = (const float*)d_in[5];
  const float* Whs = (const float*)d_in[6];
  const float* bs  = (const float*)d_in[7];
  const float* Wb  = (const float*)d_in[8];
  const float* bb  = (const float*)d_in[9];
  const float* Wk  = (const float*)d_in[10];
  const float* bk  = (const float*)d_in[11];
  // d_in[12] Wq, d_in[13] bq, d_in[15] bl: cancel in row-softmax -> unused
  const float* Wl  = (const float*)d_in[14];
  const float* Wd  = (const float*)d_in[16];
  const float* bd  = (const float*)d_in[17];
  // d_in[18] skip_mask is structurally triu -> computed as (j >= i)
  const int* tix = (const int*)d_in[19];
  const int* fix = (const int*)d_in[20];
  const int* ei  = (const int*)d_in[21];
  float* out = (float*)d_out;

  k_init<<<256, 128, 0, stream>>>();
  k_xg<<<256, 128, 0, stream>>>(NE, Wx, b);
  k_xsgates<<<dim3(512, 4), 256, 0, stream>>>(SE, Wxs, bs);
  k_kterm<<<512, 256, 0, stream>>>(SE, Wk, bk, Wl);
  k_softmax<<<256, 256, 0, stream>>>();
  for (int s = 0; s < 4; ++s) {
    k_node<<<64, 128, 0, stream>>>(Wh, Whs, Wb, bb, tix, fix);
    k_skip<<<dim3(256, 8), 128, 0, stream>>>();
    k_finish<<<256, 128, 0, stream>>>();
  }
  k_out<<<1, 64, 0, stream>>>(Wd, bd, ei, out);
}

// Round 2
// 246.296 us; speedup vs baseline: 1.1805x; 1.1805x over previous
//
#include <hip/hip_runtime.h>
#include <hip/hip_bf16.h>

constexpr int NN = 256;
constexpr int HH = 128;
constexpr int GG = 512;   // 4H
constexpr int NP = NN * NN;

typedef __attribute__((ext_vector_type(8))) short short8;
typedef __attribute__((ext_vector_type(4))) float f32x4;

// static device scratch
__device__ unsigned short g_xs[(size_t)NP * GG]; // bf16: SE@Wxs+bs, layout [pair][h][gate]
__device__ unsigned short g_wpk[5 * 128 * 128];  // packed B^T bf16 [tile][col][k], swizzled
__device__ float g_kterm[NP];
__device__ float g_yesw[NP];    // skip_dec, zero diagonal & lower-tri
__device__ float g_noskip[NN];  // diag(skip_dec)
__device__ float g_xg[NN * GG]; // node_emb@Wx + b
__device__ float g_hws[NN * HH * 4]; // h@Whs, layout [i][h][gate]
__device__ float g_c[NN * HH];
__device__ float g_h[NN * HH];
__device__ float g_sc[NN * HH];
__device__ float g_sh[NN * HH];
__device__ float g_ip[NN];
__device__ float g_nip[NN];

__device__ __forceinline__ unsigned short f2bf(float f) {
  unsigned int u = __float_as_uint(f);
  u = (u + 0x7fffu + ((u >> 16) & 1u)) >> 16;
  return (unsigned short)u;
}
__device__ __forceinline__ float bf2f(unsigned short s) {
  return __uint_as_float(((unsigned int)s) << 16);
}
__device__ __forceinline__ float frcp(float x) {
#if __has_builtin(__builtin_amdgcn_rcpf)
  return __builtin_amdgcn_rcpf(x);
#else
  return 1.0f / x;
#endif
}
__device__ __forceinline__ float sigm(float x) { return frcp(1.f + __expf(-x)); }
__device__ __forceinline__ float tanhfast(float x) { return 1.f - 2.f * frcp(__expf(2.f * x) + 1.f); }

// ---------------- init ----------------
__global__ void k_init() {
  int idx = blockIdx.x * blockDim.x + threadIdx.x; // 32768 threads
  g_sc[idx] = 0.f; g_sh[idx] = 0.f; g_c[idx] = 0.f; g_h[idx] = 0.f;
  if (idx < NN) { g_nip[idx] = 0.f; g_ip[idx] = (idx == 0) ? 1.f : 0.f; }
}

// ---------------- weight pack: B^T bf16 [tile][col][k], read-swizzle pre-applied ----------------
__global__ __launch_bounds__(128) void k_prep(const float* __restrict__ Wxs,
                                              const float* __restrict__ Wk) {
  const int tile = blockIdx.x;   // 0..4
  const int c = blockIdx.y;      // 0..127
  const int k = threadIdx.x;     // 0..127
  float v = (tile < 4) ? Wxs[k * GG + tile * 128 + c] : Wk[k * HH + c];
  char* base = (char*)g_wpk + tile * 32768;
  *(unsigned short*)(base + c * 256 + ((k * 2) ^ ((c & 7) << 4))) = f2bf(v);
}

// ---------------- xg = node_emb @ Wx + b ----------------
__global__ __launch_bounds__(128) void k_xg(const float* __restrict__ NE,
                                            const float* __restrict__ Wx,
                                            const float* __restrict__ b) {
  const int i = blockIdx.x, t = threadIdx.x;
  __shared__ float ne[HH];
  ne[t] = NE[i * HH + t];
  __syncthreads();
  float a0 = b[t], a1 = b[128 + t], a2 = b[256 + t], a3 = b[384 + t];
  for (int k = 0; k < HH; ++k) {
    float x = ne[k];
    a0 = fmaf(x, Wx[k * GG + t], a0);
    a1 = fmaf(x, Wx[k * GG + 128 + t], a1);
    a2 = fmaf(x, Wx[k * GG + 256 + t], a2);
    a3 = fmaf(x, Wx[k * GG + 384 + t], a3);
  }
  g_xg[i * GG + t] = a0; g_xg[i * GG + 128 + t] = a1;
  g_xg[i * GG + 256 + t] = a2; g_xg[i * GG + 384 + t] = a3;
}

// ---------------- fused GEMM: xs_gates (tiles 0-3) + kterm (tile 4) ----------------
// A: SE tile 128 pairs x 128 K staged once (f32->bf16, swizzled).
// B: 5 tiles of 128 cols from pre-packed bf16 (straight vector copy).
__global__ __launch_bounds__(256) void k_gemm(const float* __restrict__ SE,
                                              const float* __restrict__ bs,
                                              const float* __restrict__ bk,
                                              const float* __restrict__ Wl) {
  __shared__ __align__(16) char lds[65536];
  const int pb = blockIdx.x;  // 512 pair-tiles
  const int i_row = pb >> 1;
  const int jlo = (pb & 1) * 128;
  if (jlo + 127 < i_row) return; // no j >= i anywhere in this tile
  const int pairBase = pb * 128;
  const int tid = threadIdx.x;

  // A: [row][k] f32->bf16, swizzled (byte ^= (row&7)<<4)
  for (int cc = tid; cc < 2048; cc += 256) {
    int row = cc >> 4, kc = cc & 15;
    const float* src = SE + (size_t)(pairBase + row) * HH + kc * 8;
    float4 f0 = *(const float4*)(src);
    float4 f1 = *(const float4*)(src + 4);
    short8 v;
    v[0] = (short)f2bf(f0.x); v[1] = (short)f2bf(f0.y); v[2] = (short)f2bf(f0.z); v[3] = (short)f2bf(f0.w);
    v[4] = (short)f2bf(f1.x); v[5] = (short)f2bf(f1.y); v[6] = (short)f2bf(f1.z); v[7] = (short)f2bf(f1.w);
    *(short8*)(lds + row * 256 + ((kc * 16) ^ ((row & 7) << 4))) = v;
  }
  __syncthreads();

  const int wv = tid >> 6;
  const int l = tid & 63;
  const int l15 = l & 15, lg = l >> 4;

  // hoist A fragments to registers (reused across all 5 B-tiles)
  short8 afr[4][2];
#pragma unroll
  for (int ks = 0; ks < 4; ++ks) {
    const int kb = ks * 64 + lg * 16;
#pragma unroll
    for (int rt = 0; rt < 2; ++rt) {
      int row = wv * 32 + rt * 16 + l15;
      afr[ks][rt] = *(const short8*)(lds + row * 256 + (kb ^ ((row & 7) << 4)));
    }
  }

  for (int tile = 0; tile < 5; ++tile) {
    __syncthreads(); // previous tile's B reads done before overwrite
    // B stage: straight 16B copy of pre-swizzled pack (conflict-free)
    {
      const char* src = (const char*)g_wpk + tile * 32768;
#pragma unroll
      for (int it = 0; it < 8; ++it) {
        int off = it * 4096 + tid * 16;
        *(short8*)(lds + 32768 + off) = *(const short8*)(src + off);
      }
    }
    __syncthreads();

    f32x4 acc[2][8];
#pragma unroll
    for (int rt = 0; rt < 2; ++rt)
#pragma unroll
      for (int ct = 0; ct < 8; ++ct) acc[rt][ct] = (f32x4){0.f, 0.f, 0.f, 0.f};

#pragma unroll
    for (int ks = 0; ks < 4; ++ks) {
      const int kb = ks * 64 + lg * 16;
      short8 bfr[8];
#pragma unroll
      for (int ct = 0; ct < 8; ++ct) {
        int col = ct * 16 + l15;
        bfr[ct] = *(const short8*)(lds + 32768 + col * 256 + (kb ^ ((col & 7) << 4)));
      }
#pragma unroll
      for (int rt = 0; rt < 2; ++rt)
#pragma unroll
        for (int ct = 0; ct < 8; ++ct)
          acc[rt][ct] = __builtin_amdgcn_mfma_f32_16x16x32_bf16(afr[ks][rt], bfr[ct], acc[rt][ct], 0, 0, 0);
    }

    if (tile < 4) {
      // write gate `tile` into g_xs [pair][h][gate]
#pragma unroll
      for (int rt = 0; rt < 2; ++rt)
#pragma unroll
        for (int ct = 0; ct < 8; ++ct) {
          const int col = ct * 16 + l15;  // h index
          const float bsv = bs[tile * 128 + col];
#pragma unroll
          for (int r = 0; r < 4; ++r) {
            int row = wv * 32 + rt * 16 + lg * 4 + r;
            int pair = pairBase + row;
            int jj = pair & 255, ii = pair >> 8;
            if (jj > ii) g_xs[((size_t)pair * 128 + col) * 4 + tile] = f2bf(acc[rt][ct][r] + bsv);
          }
        }
    } else {
      // kterm: sum_h relu(x + bk) * Wl[h]
#pragma unroll
      for (int rt = 0; rt < 2; ++rt) {
#pragma unroll
        for (int r = 0; r < 4; ++r) {
          float s = 0.f;
#pragma unroll
          for (int ct = 0; ct < 8; ++ct) {
            int col = ct * 16 + l15;
            float x = acc[rt][ct][r] + bk[col];
            x = fmaxf(x, 0.f);
            s = fmaf(x, Wl[col], s);
          }
#pragma unroll
          for (int m = 1; m < 16; m <<= 1) s += __shfl_xor(s, m, 64);
          int row = wv * 32 + rt * 16 + lg * 4 + r;
          int pair = pairBase + row;
          int jj = pair & 255, ii = pair >> 8;
          if (l15 == 0 && jj >= ii) g_kterm[pair] = s;
        }
      }
    }
  }
}

// ---------------- masked row softmax -> yes_skip, no_skip ----------------
__global__ __launch_bounds__(256) void k_softmax() {
  const int i = blockIdx.x, j = threadIdx.x;
  __shared__ float sm[NN];
  float x = -1e30f;
  if (j >= i) x = g_kterm[i * NN + j];
  sm[j] = x;
  __syncthreads();
  for (int s = 128; s > 0; s >>= 1) { if (j < s) sm[j] = fmaxf(sm[j], sm[j + s]); __syncthreads(); }
  float mx = sm[0];
  __syncthreads();
  float e = (j >= i) ? __expf(x - mx) : 0.f;
  sm[j] = e;
  __syncthreads();
  for (int s = 128; s > 0; s >>= 1) { if (j < s) sm[j] += sm[j + s]; __syncthreads(); }
  float p = e * frcp(sm[0]);
  g_yesw[i * NN + j] = (j == i) ? 0.f : p;
  if (j == i) g_noskip[i] = p;
}

// ---------------- per-step: node LSTM, branch, scatter, h@Whs ----------------
__global__ __launch_bounds__(128) void k_node(const float* __restrict__ Wh,
                                              const float* __restrict__ Whs,
                                              const float* __restrict__ Wb,
                                              const float* __restrict__ bb,
                                              const int* __restrict__ tix,
                                              const int* __restrict__ fix) {
  const int i0 = blockIdx.x * 4;
  const int t = threadIdx.x;
  __shared__ float hsm[4][HH];
  __shared__ float red[2][4][2];
#pragma unroll
  for (int ii = 0; ii < 4; ++ii) hsm[ii][t] = g_h[(i0 + ii) * HH + t];
  __syncthreads();
  float aW[4][4], aS[4][4];
#pragma unroll
  for (int g = 0; g < 4; ++g)
#pragma unroll
    for (int ii = 0; ii < 4; ++ii) { aW[g][ii] = g_xg[(i0 + ii) * GG + g * 128 + t]; aS[g][ii] = 0.f; }
  for (int k = 0; k < HH; ++k) {
#pragma unroll
    for (int g = 0; g < 4; ++g) {
      float w1 = Wh[k * GG + g * 128 + t];
      float w2 = Whs[k * GG + g * 128 + t];
#pragma unroll
      for (int ii = 0; ii < 4; ++ii) {
        float hv = hsm[ii][k];
        aW[g][ii] = fmaf(hv, w1, aW[g][ii]);
        aS[g][ii] = fmaf(hv, w2, aS[g][ii]);
      }
    }
  }
#pragma unroll
  for (int ii = 0; ii < 4; ++ii) {
    float4 v = make_float4(aS[0][ii], aS[1][ii], aS[2][ii], aS[3][ii]);
    *(float4*)&g_hws[((size_t)(i0 + ii) * HH + t) * 4] = v;
  }
  float cp[4], hp[4];
#pragma unroll
  for (int ii = 0; ii < 4; ++ii) {
    float co = g_c[(i0 + ii) * HH + t];
    float c2 = sigm(aW[1][ii]) * co + sigm(aW[0][ii]) * tanhfast(aW[2][ii]);
    float h2 = sigm(aW[3][ii]) * tanhfast(c2);
    cp[ii] = c2; hp[ii] = h2;
  }
  float wb0 = Wb[2 * t], wb1 = Wb[2 * t + 1];
  float wb0h = Wb[2 * (128 + t)], wb1h = Wb[2 * (128 + t) + 1];
#pragma unroll
  for (int ii = 0; ii < 4; ++ii) {
    float q0 = cp[ii] * wb0 + hp[ii] * wb0h;
    float q1 = cp[ii] * wb1 + hp[ii] * wb1h;
#pragma unroll
    for (int m = 1; m < 64; m <<= 1) { q0 += __shfl_xor(q0, m, 64); q1 += __shfl_xor(q1, m, 64); }
    if ((t & 63) == 0) { red[t >> 6][ii][0] = q0; red[t >> 6][ii][1] = q1; }
  }
  __syncthreads();
#pragma unroll
  for (int ii = 0; ii < 4; ++ii) {
    float l0 = red[0][ii][0] + red[1][ii][0] + bb[0];
    float l1 = red[0][ii][1] + red[1][ii][1] + bb[1];
    float mm = fmaxf(l0, l1);
    float e0 = __expf(l0 - mm), e1 = __expf(l1 - mm);
    float inv = frcp(e0 + e1);
    float ipv = g_ip[i0 + ii] * g_noskip[i0 + ii];
    if (ipv != 0.f) {
      float pbt = ipv * e0 * inv, pbf = ipv * e1 * inv;
      int ti = tix[i0 + ii], fi = fix[i0 + ii];
      atomicAdd(&g_sc[ti * HH + t], cp[ii] * pbt);
      atomicAdd(&g_sh[ti * HH + t], hp[ii] * pbt);
      atomicAdd(&g_sc[fi * HH + t], cp[ii] * pbf);
      atomicAdd(&g_sh[fi * HH + t], hp[ii] * pbf);
      if (t == 0) { atomicAdd(&g_nip[ti], pbt); atomicAdd(&g_nip[fi], pbf); }
    }
  }
}

// ---------------- per-step: skip LSTM + weighted aggregation ----------------
__global__ __launch_bounds__(128) void k_skip() {
  const int j = blockIdx.x, ic = blockIdx.y, t = threadIdx.x;
  const int i0 = ic * 16;
  if (i0 >= j) return;
  const int i1 = (i0 + 16 < j) ? (i0 + 16) : j;
  float accC = 0.f, accH = 0.f, accW = 0.f;
  for (int i = i0; i < i1; ++i) {
    float wgt = g_ip[i] * g_yesw[i * NN + j];
    if (wgt == 0.f) continue;
    // all 4 gates for h=t in one 8B load
    const ushort4 gv = *(const ushort4*)&g_xs[((size_t)(i * NN + j) * 128 + t) * 4];
    float4 hw = *(const float4*)&g_hws[((size_t)i * HH + t) * 4];
    float xi = bf2f(gv.x) + hw.x;
    float xf = bf2f(gv.y) + hw.y;
    float xg = bf2f(gv.z) + hw.z;
    float xo = bf2f(gv.w) + hw.w;
    float c2 = sigm(xf) * g_c[i * HH + t] + sigm(xi) * tanhfast(xg);
    float h2 = sigm(xo) * tanhfast(c2);
    accC = fmaf(wgt, c2, accC);
    accH = fmaf(wgt, h2, accH);
    accW += wgt;
  }
  if (accW != 0.f) {
    atomicAdd(&g_sc[j * HH + t], accC);
    atomicAdd(&g_sh[j * HH + t], accH);
    if (t == 0) atomicAdd(&g_nip[j], accW);
  }
}

// ---------------- per-step: finalize carry, zero accumulators ----------------
__global__ __launch_bounds__(128) void k_finish() {
  const int j = blockIdx.x, t = threadIdx.x;
  float nip = g_nip[j];
  float d = 1.f / (nip + 1e-7f);
  g_c[j * HH + t] = g_sc[j * HH + t] * d;
  g_h[j * HH + t] = g_sh[j * HH + t] * d;
  g_sc[j * HH + t] = 0.f;
  g_sh[j * HH + t] = 0.f;
  if (t == 0) { g_ip[j] = nip; g_nip[j] = 0.f; }
}

// ---------------- output: [c[exit], h[exit]] @ Wd + bd ----------------
__global__ __launch_bounds__(64) void k_out(const float* __restrict__ Wd,
                                            const float* __restrict__ bd,
                                            const int* __restrict__ ei,
                                            float* __restrict__ out) {
  const int v = threadIdx.x;
  const int e = ei[0];
  float s = bd[v];
  for (int h = 0; h < HH; ++h) {
    s = fmaf(g_c[e * HH + h], Wd[h * 64 + v], s);
    s = fmaf(g_h[e * HH + h], Wd[(128 + h) * 64 + v], s);
  }
  out[v] = s;
}

extern "C" void kernel_launch(void* const* d_in, const int* in_sizes, int n_in,
                              void* d_out, int out_size, void* d_ws, size_t ws_size,
                              hipStream_t stream) {
  const float* NE  = (const float*)d_in[0];
  const float* SE  = (const float*)d_in[1];
  const float* Wx  = (const float*)d_in[2];
  const float* Wh  = (const float*)d_in[3];
  const float* b   = (const float*)d_in[4];
  const float* Wxs = (const float*)d_in[5];
  const float* Whs = (const float*)d_in[6];
  const float* bs  = (const float*)d_in[7];
  const float* Wb  = (const float*)d_in[8];
  const float* bb  = (const float*)d_in[9];
  const float* Wk  = (const float*)d_in[10];
  const float* bk  = (const float*)d_in[11];
  // d_in[12] Wq, d_in[13] bq, d_in[15] bl: cancel in row-softmax -> unused
  const float* Wl  = (const float*)d_in[14];
  const float* Wd  = (const float*)d_in[16];
  const float* bd  = (const float*)d_in[17];
  // d_in[18] skip_mask is structurally triu -> computed as (j >= i)
  const int* tix = (const int*)d_in[19];
  const int* fix = (const int*)d_in[20];
  const int* ei  = (const int*)d_in[21];
  float* out = (float*)d_out;

  k_init<<<256, 128, 0, stream>>>();
  k_prep<<<dim3(5, 128), 128, 0, stream>>>(Wxs, Wk);
  k_xg<<<256, 128, 0, stream>>>(NE, Wx, b);
  k_gemm<<<512, 256, 0, stream>>>(SE, bs, bk, Wl);
  k_softmax<<<256, 256, 0, stream>>>();
  for (int s = 0; s < 4; ++s) {
    k_node<<<64, 128, 0, stream>>>(Wh, Whs, Wb, bb, tix, fix);
    k_skip<<<dim3(256, 16), 128, 0, stream>>>();
    k_finish<<<256, 128, 0, stream>>>();
  }
  k_out<<<1, 64, 0, stream>>>(Wd, bd, ei, out);
}

// Round 3
// 181.084 us; speedup vs baseline: 1.6057x; 1.3601x over previous
//
#include <hip/hip_runtime.h>
#include <hip/hip_bf16.h>

constexpr int NN = 256;
constexpr int HH = 128;
constexpr int GG = 512;   // 4H
constexpr int NP = NN * NN;

typedef __attribute__((ext_vector_type(8))) short short8;
typedef __attribute__((ext_vector_type(4))) float f32x4;

// static device scratch
__device__ unsigned short g_xs[(size_t)NP * GG]; // bf16: SE@Wxs+bs, layout [pair][h][gate] (col' = h*4+g)
__device__ unsigned short g_wpk[5 * 128 * 128];  // packed B^T bf16 [tile][col'][k], swizzled
__device__ float g_bsp[GG];                      // bs permuted to col' order
__device__ float g_pwh[HH * HH * 4];             // Wh packed [k][t][gate]
__device__ float g_pws[HH * HH * 4];             // Whs packed [k][t][gate]
__device__ float g_kterm[NP];
__device__ float g_yesw[NP];    // skip_dec, zero diagonal & lower-tri
__device__ float g_noskip[NN];  // diag(skip_dec)
__device__ float g_xg[NN * GG]; // node_emb@Wx + b
__device__ float g_hws[NN * HH * 4]; // h@Whs, layout [i][h][gate]
__device__ float g_c[NN * HH];
__device__ float g_h[NN * HH];
__device__ float g_sc[NN * HH];
__device__ float g_sh[NN * HH];
__device__ float g_ip[NN];
__device__ float g_nip[NN];

__device__ __forceinline__ unsigned short f2bf(float f) {
  unsigned int u = __float_as_uint(f);
  u = (u + 0x7fffu + ((u >> 16) & 1u)) >> 16;
  return (unsigned short)u;
}
__device__ __forceinline__ float bf2f(unsigned short s) {
  return __uint_as_float(((unsigned int)s) << 16);
}
__device__ __forceinline__ float frcp(float x) {
#if __has_builtin(__builtin_amdgcn_rcpf)
  return __builtin_amdgcn_rcpf(x);
#else
  return 1.0f / x;
#endif
}
__device__ __forceinline__ float sigm(float x) { return frcp(1.f + __expf(-x)); }
__device__ __forceinline__ float tanhfast(float x) { return 1.f - 2.f * frcp(__expf(2.f * x) + 1.f); }

// ---------------- init ----------------
__global__ void k_init() {
  int idx = blockIdx.x * blockDim.x + threadIdx.x; // 32768 threads
  g_sc[idx] = 0.f; g_sh[idx] = 0.f; g_c[idx] = 0.f; g_h[idx] = 0.f;
  *(float4*)&g_hws[(size_t)idx * 4] = make_float4(0.f, 0.f, 0.f, 0.f);
  if (idx < NN) { g_nip[idx] = 0.f; g_ip[idx] = (idx == 0) ? 1.f : 0.f; }
}

// ---------------- weight pack: B^T bf16 [tile][col'][k], read-swizzle pre-applied ----------------
// tiles 0-3: col' = t*128+c maps to Wxs column (c&3)*128 + t*32 + (c>>2)  (c' = h*4+g)
// tile 4: Wk, col' = h directly
__global__ __launch_bounds__(128) void k_prep(const float* __restrict__ Wxs,
                                              const float* __restrict__ Wk,
                                              const float* __restrict__ bs) {
  const int tile = blockIdx.x;   // 0..4
  const int c = blockIdx.y;      // 0..127
  const int k = threadIdx.x;     // 0..127
  float v;
  if (tile < 4) {
    const int src = (c & 3) * 128 + tile * 32 + (c >> 2);
    v = Wxs[k * GG + src];
    if (k == 0) g_bsp[tile * 128 + c] = bs[src];
  } else {
    v = Wk[k * HH + c];
  }
  char* base = (char*)g_wpk + tile * 32768;
  *(unsigned short*)(base + c * 256 + ((k * 2) ^ ((c & 7) << 4))) = f2bf(v);
}

// ---------------- pack Wh/Whs as [k][t][gate] float4 ----------------
__global__ __launch_bounds__(128) void k_prep2(const float* __restrict__ Wh,
                                               const float* __restrict__ Whs) {
  const int k = blockIdx.x, t = threadIdx.x;
  float4 a = make_float4(Wh[k * GG + t], Wh[k * GG + 128 + t], Wh[k * GG + 256 + t], Wh[k * GG + 384 + t]);
  float4 s = make_float4(Whs[k * GG + t], Whs[k * GG + 128 + t], Whs[k * GG + 256 + t], Whs[k * GG + 384 + t]);
  *(float4*)&g_pwh[((size_t)k * HH + t) * 4] = a;
  *(float4*)&g_pws[((size_t)k * HH + t) * 4] = s;
}

// ---------------- xg = node_emb @ Wx + b ----------------
__global__ __launch_bounds__(128) void k_xg(const float* __restrict__ NE,
                                            const float* __restrict__ Wx,
                                            const float* __restrict__ b) {
  const int i = blockIdx.x, t = threadIdx.x;
  __shared__ float ne[HH];
  ne[t] = NE[i * HH + t];
  __syncthreads();
  float a0 = b[t], a1 = b[128 + t], a2 = b[256 + t], a3 = b[384 + t];
  for (int k = 0; k < HH; ++k) {
    float x = ne[k];
    a0 = fmaf(x, Wx[k * GG + t], a0);
    a1 = fmaf(x, Wx[k * GG + 128 + t], a1);
    a2 = fmaf(x, Wx[k * GG + 256 + t], a2);
    a3 = fmaf(x, Wx[k * GG + 384 + t], a3);
  }
  g_xg[i * GG + t] = a0; g_xg[i * GG + 128 + t] = a1;
  g_xg[i * GG + 256 + t] = a2; g_xg[i * GG + 384 + t] = a3;
}

// ---------------- fused GEMM: xs_gates (tiles 0-3, permuted cols) + kterm (tile 4) ----------------
__global__ __launch_bounds__(256) void k_gemm(const float* __restrict__ SE,
                                              const float* __restrict__ bk,
                                              const float* __restrict__ Wl) {
  __shared__ __align__(16) char lds[65536];
  const int pb = blockIdx.x;  // 512 pair-tiles
  const int i_row = pb >> 1;
  const int jlo = (pb & 1) * 128;
  if (jlo + 127 < i_row) return; // no j >= i anywhere in this tile
  const int pairBase = pb * 128;
  const int tid = threadIdx.x;

  // A: [row][k] f32->bf16, swizzled (byte ^= (row&7)<<4)
  for (int cc = tid; cc < 2048; cc += 256) {
    int row = cc >> 4, kc = cc & 15;
    const float* src = SE + (size_t)(pairBase + row) * HH + kc * 8;
    float4 f0 = *(const float4*)(src);
    float4 f1 = *(const float4*)(src + 4);
    short8 v;
    v[0] = (short)f2bf(f0.x); v[1] = (short)f2bf(f0.y); v[2] = (short)f2bf(f0.z); v[3] = (short)f2bf(f0.w);
    v[4] = (short)f2bf(f1.x); v[5] = (short)f2bf(f1.y); v[6] = (short)f2bf(f1.z); v[7] = (short)f2bf(f1.w);
    *(short8*)(lds + row * 256 + ((kc * 16) ^ ((row & 7) << 4))) = v;
  }
  __syncthreads();

  const int wv = tid >> 6;
  const int l = tid & 63;
  const int l15 = l & 15, lg = l >> 4;

  // hoist A fragments to registers (reused across all 5 B-tiles)
  short8 afr[4][2];
#pragma unroll
  for (int ks = 0; ks < 4; ++ks) {
    const int kb = ks * 64 + lg * 16;
#pragma unroll
    for (int rt = 0; rt < 2; ++rt) {
      int row = wv * 32 + rt * 16 + l15;
      afr[ks][rt] = *(const short8*)(lds + row * 256 + (kb ^ ((row & 7) << 4)));
    }
  }

  for (int tile = 0; tile < 5; ++tile) {
    __syncthreads(); // previous tile's B reads done before overwrite
    {
      const char* src = (const char*)g_wpk + tile * 32768;
#pragma unroll
      for (int it = 0; it < 8; ++it) {
        int off = it * 4096 + tid * 16;
        *(short8*)(lds + 32768 + off) = *(const short8*)(src + off);
      }
    }
    __syncthreads();

    f32x4 acc[2][8];
#pragma unroll
    for (int rt = 0; rt < 2; ++rt)
#pragma unroll
      for (int ct = 0; ct < 8; ++ct) acc[rt][ct] = (f32x4){0.f, 0.f, 0.f, 0.f};

#pragma unroll
    for (int ks = 0; ks < 4; ++ks) {
      const int kb = ks * 64 + lg * 16;
      short8 bfr[8];
#pragma unroll
      for (int ct = 0; ct < 8; ++ct) {
        int col = ct * 16 + l15;
        bfr[ct] = *(const short8*)(lds + 32768 + col * 256 + (kb ^ ((col & 7) << 4)));
      }
#pragma unroll
      for (int rt = 0; rt < 2; ++rt)
#pragma unroll
        for (int ct = 0; ct < 8; ++ct)
          acc[rt][ct] = __builtin_amdgcn_mfma_f32_16x16x32_bf16(afr[ks][rt], bfr[ct], acc[rt][ct], 0, 0, 0);
    }

    if (tile < 4) {
      // contiguous stores: g_xs[pair*512 + tile*128 + col] (col' = h*4+g layout)
#pragma unroll
      for (int rt = 0; rt < 2; ++rt)
#pragma unroll
        for (int ct = 0; ct < 8; ++ct) {
          const int col = ct * 16 + l15;
          const float bsv = g_bsp[tile * 128 + col];
#pragma unroll
          for (int r = 0; r < 4; ++r) {
            int row = wv * 32 + rt * 16 + lg * 4 + r;
            int pair = pairBase + row;
            int jj = pair & 255, ii = pair >> 8;
            if (jj > ii) g_xs[(size_t)pair * GG + tile * 128 + col] = f2bf(acc[rt][ct][r] + bsv);
          }
        }
    } else {
      // kterm: sum_h relu(x + bk) * Wl[h]
#pragma unroll
      for (int rt = 0; rt < 2; ++rt) {
#pragma unroll
        for (int r = 0; r < 4; ++r) {
          float s = 0.f;
#pragma unroll
          for (int ct = 0; ct < 8; ++ct) {
            int col = ct * 16 + l15;
            float x = acc[rt][ct][r] + bk[col];
            x = fmaxf(x, 0.f);
            s = fmaf(x, Wl[col], s);
          }
#pragma unroll
          for (int m = 1; m < 16; m <<= 1) s += __shfl_xor(s, m, 64);
          int row = wv * 32 + rt * 16 + lg * 4 + r;
          int pair = pairBase + row;
          int jj = pair & 255, ii = pair >> 8;
          if (l15 == 0 && jj >= ii) g_kterm[pair] = s;
        }
      }
    }
  }
}

// ---------------- masked row softmax -> yes_skip, no_skip ----------------
__global__ __launch_bounds__(256) void k_softmax() {
  const int i = blockIdx.x, j = threadIdx.x;
  __shared__ float sm[NN];
  float x = -1e30f;
  if (j >= i) x = g_kterm[i * NN + j];
  sm[j] = x;
  __syncthreads();
  for (int s = 128; s > 0; s >>= 1) { if (j < s) sm[j] = fmaxf(sm[j], sm[j + s]); __syncthreads(); }
  float mx = sm[0];
  __syncthreads();
  float e = (j >= i) ? __expf(x - mx) : 0.f;
  sm[j] = e;
  __syncthreads();
  for (int s = 128; s > 0; s >>= 1) { if (j < s) sm[j] += sm[j + s]; __syncthreads(); }
  float p = e * frcp(sm[0]);
  g_yesw[i * NN + j] = (j == i) ? 0.f : p;
  if (j == i) g_noskip[i] = p;
}

// ---------------- per-step fused: node LSTM/branch/scatter (blocks 0-255)
//                  + skip LSTM/aggregate (blocks 256+) ----------------
__global__ __launch_bounds__(128) void k_step(const float* __restrict__ Wb,
                                              const float* __restrict__ bb,
                                              const int* __restrict__ tix,
                                              const int* __restrict__ fix) {
  const int t = threadIdx.x;
  __shared__ float hsm[HH];
  __shared__ float red[2][2];
  if (blockIdx.x < 256) {
    const int i = blockIdx.x;
    hsm[t] = g_h[i * HH + t];
    __syncthreads();
    float a0 = g_xg[i * GG + t], a1 = g_xg[i * GG + 128 + t];
    float a2 = g_xg[i * GG + 256 + t], a3 = g_xg[i * GG + 384 + t];
    for (int k = 0; k < HH; ++k) {
      float hv = hsm[k];
      const float4 wa = *(const float4*)&g_pwh[((size_t)k * HH + t) * 4];
      a0 = fmaf(hv, wa.x, a0); a1 = fmaf(hv, wa.y, a1);
      a2 = fmaf(hv, wa.z, a2); a3 = fmaf(hv, wa.w, a3);
    }
    float co = g_c[i * HH + t];
    float c2 = sigm(a1) * co + sigm(a0) * tanhfast(a2);
    float h2 = sigm(a3) * tanhfast(c2);
    // branch logits: block-wide reduction over [c2;h2] . Wb
    float q0 = c2 * Wb[2 * t] + h2 * Wb[2 * (128 + t)];
    float q1 = c2 * Wb[2 * t + 1] + h2 * Wb[2 * (128 + t) + 1];
#pragma unroll
    for (int m = 1; m < 64; m <<= 1) { q0 += __shfl_xor(q0, m, 64); q1 += __shfl_xor(q1, m, 64); }
    if ((t & 63) == 0) { red[t >> 6][0] = q0; red[t >> 6][1] = q1; }
    __syncthreads();
    float l0 = red[0][0] + red[1][0] + bb[0];
    float l1 = red[0][1] + red[1][1] + bb[1];
    float mm = fmaxf(l0, l1);
    float e0 = __expf(l0 - mm), e1 = __expf(l1 - mm);
    float inv = frcp(e0 + e1);
    float ipv = g_ip[i] * g_noskip[i];
    if (ipv != 0.f) {
      float pbt = ipv * e0 * inv, pbf = ipv * e1 * inv;
      int ti = tix[i], fi = fix[i];
      atomicAdd(&g_sc[ti * HH + t], c2 * pbt);
      atomicAdd(&g_sh[ti * HH + t], h2 * pbt);
      atomicAdd(&g_sc[fi * HH + t], c2 * pbf);
      atomicAdd(&g_sh[fi * HH + t], h2 * pbf);
      if (t == 0) { atomicAdd(&g_nip[ti], pbt); atomicAdd(&g_nip[fi], pbf); }
    }
  } else {
    const int idx = blockIdx.x - 256;
    const int j = idx >> 3, chunk = idx & 7;
    const int i0 = chunk * 32;
    if (i0 >= j) return;
    const int i1 = (i0 + 32 < j) ? (i0 + 32) : j;
    float accC = 0.f, accH = 0.f, accW = 0.f;
    for (int i = i0; i < i1; ++i) {
      float wgt = g_ip[i] * g_yesw[i * NN + j];
      if (wgt == 0.f) continue;
      const ushort4 gv = *(const ushort4*)&g_xs[((size_t)(i * NN + j) * 128 + t) * 4];
      float4 hw = *(const float4*)&g_hws[((size_t)i * HH + t) * 4];
      float xi = bf2f(gv.x) + hw.x;
      float xf = bf2f(gv.y) + hw.y;
      float xg = bf2f(gv.z) + hw.z;
      float xo = bf2f(gv.w) + hw.w;
      float c2 = sigm(xf) * g_c[i * HH + t] + sigm(xi) * tanhfast(xg);
      float h2 = sigm(xo) * tanhfast(c2);
      accC = fmaf(wgt, c2, accC);
      accH = fmaf(wgt, h2, accH);
      accW += wgt;
    }
    if (accW != 0.f) {
      atomicAdd(&g_sc[j * HH + t], accC);
      atomicAdd(&g_sh[j * HH + t], accH);
      if (t == 0) atomicAdd(&g_nip[j], accW);
    }
  }
}

// ---------------- per-step: finalize carry + compute hws = h@Whs for next step ----------------
__global__ __launch_bounds__(128) void k_finish() {
  const int j = blockIdx.x, t = threadIdx.x;
  __shared__ float hsm[HH];
  float nip = g_nip[j];
  float d = frcp(nip + 1e-7f);
  float cv = g_sc[j * HH + t] * d;
  float hv = g_sh[j * HH + t] * d;
  g_c[j * HH + t] = cv;
  g_h[j * HH + t] = hv;
  hsm[t] = hv;
  g_sc[j * HH + t] = 0.f;
  g_sh[j * HH + t] = 0.f;
  if (t == 0) { g_ip[j] = nip; g_nip[j] = 0.f; }
  __syncthreads();
  float s0 = 0.f, s1 = 0.f, s2 = 0.f, s3 = 0.f;
  for (int k = 0; k < HH; ++k) {
    float hk = hsm[k];
    const float4 w = *(const float4*)&g_pws[((size_t)k * HH + t) * 4];
    s0 = fmaf(hk, w.x, s0); s1 = fmaf(hk, w.y, s1);
    s2 = fmaf(hk, w.z, s2); s3 = fmaf(hk, w.w, s3);
  }
  *(float4*)&g_hws[((size_t)j * HH + t) * 4] = make_float4(s0, s1, s2, s3);
}

// ---------------- output: [c[exit], h[exit]] @ Wd + bd ----------------
__global__ __launch_bounds__(64) void k_out(const float* __restrict__ Wd,
                                            const float* __restrict__ bd,
                                            const int* __restrict__ ei,
                                            float* __restrict__ out) {
  const int v = threadIdx.x;
  const int e = ei[0];
  float s = bd[v];
  for (int h = 0; h < HH; ++h) {
    s = fmaf(g_c[e * HH + h], Wd[h * 64 + v], s);
    s = fmaf(g_h[e * HH + h], Wd[(128 + h) * 64 + v], s);
  }
  out[v] = s;
}

extern "C" void kernel_launch(void* const* d_in, const int* in_sizes, int n_in,
                              void* d_out, int out_size, void* d_ws, size_t ws_size,
                              hipStream_t stream) {
  const float* NE  = (const float*)d_in[0];
  const float* SE  = (const float*)d_in[1];
  const float* Wx  = (const float*)d_in[2];
  const float* Wh  = (const float*)d_in[3];
  const float* b   = (const float*)d_in[4];
  const float* Wxs = (const float*)d_in[5];
  const float* Whs = (const float*)d_in[6];
  const float* bs  = (const float*)d_in[7];
  const float* Wb  = (const float*)d_in[8];
  const float* bb  = (const float*)d_in[9];
  const float* Wk  = (const float*)d_in[10];
  const float* bk  = (const float*)d_in[11];
  // d_in[12] Wq, d_in[13] bq, d_in[15] bl: cancel in row-softmax -> unused
  const float* Wl  = (const float*)d_in[14];
  const float* Wd  = (const float*)d_in[16];
  const float* bd  = (const float*)d_in[17];
  // d_in[18] skip_mask is structurally triu -> computed as (j >= i)
  const int* tix = (const int*)d_in[19];
  const int* fix = (const int*)d_in[20];
  const int* ei  = (const int*)d_in[21];
  float* out = (float*)d_out;

  k_init<<<256, 128, 0, stream>>>();
  k_prep<<<dim3(5, 128), 128, 0, stream>>>(Wxs, Wk, bs);
  k_prep2<<<128, 128, 0, stream>>>(Wh, Whs);
  k_xg<<<256, 128, 0, stream>>>(NE, Wx, b);
  k_gemm<<<512, 256, 0, stream>>>(SE, bk, Wl);
  k_softmax<<<256, 256, 0, stream>>>();
  for (int s = 0; s < 4; ++s) {
    k_step<<<256 + 2048, 128, 0, stream>>>(Wb, bb, tix, fix);
    k_finish<<<256, 128, 0, stream>>>();
  }
  k_out<<<1, 64, 0, stream>>>(Wd, bd, ei, out);
}

// Round 4
// 165.716 us; speedup vs baseline: 1.7546x; 1.0927x over previous
//
#include <hip/hip_runtime.h>
#include <hip/hip_bf16.h>

constexpr int NN = 256;
constexpr int HH = 128;
constexpr int GG = 512;   // 4H
constexpr int NP = NN * NN;

typedef __attribute__((ext_vector_type(8))) short short8;
typedef __attribute__((ext_vector_type(4))) float f32x4;

// static device scratch
__device__ unsigned short g_xs[(size_t)NP * GG]; // bf16: SE@Wxs+bs, layout [pair][h][gate] (col' = h*4+g)
__device__ unsigned short g_wfr[20 * 512 * 8];   // B in MFMA-fragment order: [(tile*4+ks)][ct*64+l][8]
__device__ float g_bsp[GG];                      // bs permuted to col' order
__device__ float g_pwh[HH * HH * 4];             // Wh packed [k][t][gate]
__device__ float g_pws[HH * HH * 4];             // Whs packed [k][t][gate]
__device__ float g_kterm[NP];
__device__ float g_yesw[NP];    // skip_dec, zero diagonal & lower-tri
__device__ float g_noskip[NN];  // diag(skip_dec)
__device__ float g_xg[NN * GG]; // node_emb@Wx + b
__device__ float g_hws[NN * HH * 4]; // h@Whs, layout [i][h][gate]
__device__ float g_c[NN * HH];
__device__ float g_h[NN * HH];
__device__ float g_sc[NN * HH];
__device__ float g_sh[NN * HH];
__device__ float g_ip[NN];
__device__ float g_nip[NN];

__device__ __forceinline__ unsigned short f2bf(float f) {
  unsigned int u = __float_as_uint(f);
  u = (u + 0x7fffu + ((u >> 16) & 1u)) >> 16;
  return (unsigned short)u;
}
__device__ __forceinline__ float bf2f(unsigned short s) {
  return __uint_as_float(((unsigned int)s) << 16);
}
__device__ __forceinline__ float frcp(float x) {
#if __has_builtin(__builtin_amdgcn_rcpf)
  return __builtin_amdgcn_rcpf(x);
#else
  return 1.0f / x;
#endif
}
__device__ __forceinline__ float sigm(float x) { return frcp(1.f + __expf(-x)); }
__device__ __forceinline__ float tanhfast(float x) { return 1.f - 2.f * frcp(__expf(2.f * x) + 1.f); }

// ---------------- init ----------------
__global__ void k_init() {
  int idx = blockIdx.x * blockDim.x + threadIdx.x; // 32768 threads
  g_sc[idx] = 0.f; g_sh[idx] = 0.f; g_c[idx] = 0.f; g_h[idx] = 0.f;
  *(float4*)&g_hws[(size_t)idx * 4] = make_float4(0.f, 0.f, 0.f, 0.f);
  if (idx < NN) { g_nip[idx] = 0.f; g_ip[idx] = (idx == 0) ? 1.f : 0.f; }
}

// ---------------- weight pack: B in MFMA fragment order ----------------
// fragment (tile, ks, ct, lane l, elem e): col c = ct*16 + (l&15), k = ks*32 + (l>>4)*8 + e
// tiles 0-3: Wxs with col' permutation c' = h*4+gate -> src = (c&3)*128 + tile*32 + (c>>2)
// tile 4: Wk, col = c directly
__global__ __launch_bounds__(512) void k_prep(const float* __restrict__ Wxs,
                                              const float* __restrict__ Wk,
                                              const float* __restrict__ bs) {
  const int bidx = blockIdx.x;   // 0..19 = tile*4+ks
  const int tile = bidx >> 2, ks = bidx & 3;
  const int s = threadIdx.x;     // 0..511
  const int ct = s >> 6, l = s & 63;
  const int c = ct * 16 + (l & 15);
  const int kbase = ks * 32 + (l >> 4) * 8;
  int src = 0;
  if (tile < 4) src = (c & 3) * 128 + tile * 32 + (c >> 2);
  unsigned short* dst = &g_wfr[((size_t)bidx * 512 + s) * 8];
#pragma unroll
  for (int e = 0; e < 8; ++e) {
    int k = kbase + e;
    float v = (tile < 4) ? Wxs[k * GG + src] : Wk[k * HH + c];
    dst[e] = f2bf(v);
  }
  if (tile < 4 && ks == 0 && (l >> 4) == 0) g_bsp[tile * 128 + c] = bs[src];
}

// ---------------- pack Wh/Whs as [k][t][gate] float4 ----------------
__global__ __launch_bounds__(128) void k_prep2(const float* __restrict__ Wh,
                                               const float* __restrict__ Whs) {
  const int k = blockIdx.x, t = threadIdx.x;
  float4 a = make_float4(Wh[k * GG + t], Wh[k * GG + 128 + t], Wh[k * GG + 256 + t], Wh[k * GG + 384 + t]);
  float4 s = make_float4(Whs[k * GG + t], Whs[k * GG + 128 + t], Whs[k * GG + 256 + t], Whs[k * GG + 384 + t]);
  *(float4*)&g_pwh[((size_t)k * HH + t) * 4] = a;
  *(float4*)&g_pws[((size_t)k * HH + t) * 4] = s;
}

// ---------------- xg = node_emb @ Wx + b ----------------
__global__ __launch_bounds__(128) void k_xg(const float* __restrict__ NE,
                                            const float* __restrict__ Wx,
                                            const float* __restrict__ b) {
  const int i = blockIdx.x, t = threadIdx.x;
  __shared__ float ne[HH];
  ne[t] = NE[i * HH + t];
  __syncthreads();
  float a0 = b[t], a1 = b[128 + t], a2 = b[256 + t], a3 = b[384 + t];
  for (int k = 0; k < HH; ++k) {
    float x = ne[k];
    a0 = fmaf(x, Wx[k * GG + t], a0);
    a1 = fmaf(x, Wx[k * GG + 128 + t], a1);
    a2 = fmaf(x, Wx[k * GG + 256 + t], a2);
    a3 = fmaf(x, Wx[k * GG + 384 + t], a3);
  }
  g_xg[i * GG + t] = a0; g_xg[i * GG + 128 + t] = a1;
  g_xg[i * GG + 256 + t] = a2; g_xg[i * GG + 384 + t] = a3;
}

__device__ __forceinline__ void loadB(short8* dst, int tile, int ks, int l) {
  const unsigned short* wf = &g_wfr[((size_t)(tile * 4 + ks)) * 4096 + l * 8];
#pragma unroll
  for (int ct = 0; ct < 8; ++ct) dst[ct] = *(const short8*)(wf + ct * 512);
}

// ---------------- fused GEMM: xs_gates (tiles 0-3, permuted cols) + kterm (tile 4) ----------------
// A staged in LDS (one barrier); B read straight from global in fragment order.
__global__ __launch_bounds__(256) void k_gemm(const float* __restrict__ SE,
                                              const float* __restrict__ bk,
                                              const float* __restrict__ Wl) {
  __shared__ __align__(16) char lds[32768];
  // compact grid: 384 active pair-tiles
  const int bid = blockIdx.x;
  const int pb = (bid < 128) ? (bid * 2) : ((bid - 128) * 2 + 1);
  const int pairBase = pb * 128;
  const int tid = threadIdx.x;

  // A: [row][k] f32->bf16, swizzled (byte ^= (row&7)<<4)
  for (int cc = tid; cc < 2048; cc += 256) {
    int row = cc >> 4, kc = cc & 15;
    const float* src = SE + (size_t)(pairBase + row) * HH + kc * 8;
    float4 f0 = *(const float4*)(src);
    float4 f1 = *(const float4*)(src + 4);
    short8 v;
    v[0] = (short)f2bf(f0.x); v[1] = (short)f2bf(f0.y); v[2] = (short)f2bf(f0.z); v[3] = (short)f2bf(f0.w);
    v[4] = (short)f2bf(f1.x); v[5] = (short)f2bf(f1.y); v[6] = (short)f2bf(f1.z); v[7] = (short)f2bf(f1.w);
    *(short8*)(lds + row * 256 + ((kc * 16) ^ ((row & 7) << 4))) = v;
  }
  __syncthreads();

  const int wv = tid >> 6;
  const int l = tid & 63;
  const int l15 = l & 15, lg = l >> 4;

#pragma unroll 1
  for (int tile = 0; tile < 5; ++tile) {
    f32x4 acc[2][8];
#pragma unroll
    for (int rt = 0; rt < 2; ++rt)
#pragma unroll
      for (int ct = 0; ct < 8; ++ct) acc[rt][ct] = (f32x4){0.f, 0.f, 0.f, 0.f};

    short8 bA[8], bB[8];
    loadB(bA, tile, 0, l);
#pragma unroll
    for (int ks = 0; ks < 4; ks += 2) {
      loadB(bB, tile, ks + 1, l);
      {
        const int kb = ks * 64 + lg * 16;
        short8 a[2];
#pragma unroll
        for (int rt = 0; rt < 2; ++rt) {
          int row = wv * 32 + rt * 16 + l15;
          a[rt] = *(const short8*)(lds + row * 256 + (kb ^ ((row & 7) << 4)));
        }
#pragma unroll
        for (int rt = 0; rt < 2; ++rt)
#pragma unroll
          for (int ct = 0; ct < 8; ++ct)
            acc[rt][ct] = __builtin_amdgcn_mfma_f32_16x16x32_bf16(a[rt], bA[ct], acc[rt][ct], 0, 0, 0);
      }
      if (ks + 2 < 4) loadB(bA, tile, ks + 2, l);
      {
        const int kb = (ks + 1) * 64 + lg * 16;
        short8 a[2];
#pragma unroll
        for (int rt = 0; rt < 2; ++rt) {
          int row = wv * 32 + rt * 16 + l15;
          a[rt] = *(const short8*)(lds + row * 256 + (kb ^ ((row & 7) << 4)));
        }
#pragma unroll
        for (int rt = 0; rt < 2; ++rt)
#pragma unroll
          for (int ct = 0; ct < 8; ++ct)
            acc[rt][ct] = __builtin_amdgcn_mfma_f32_16x16x32_bf16(a[rt], bB[ct], acc[rt][ct], 0, 0, 0);
      }
    }

    if (tile < 4) {
      // contiguous stores: g_xs[pair*512 + tile*128 + col] (col' = h*4+g layout)
#pragma unroll
      for (int rt = 0; rt < 2; ++rt)
#pragma unroll
        for (int ct = 0; ct < 8; ++ct) {
          const int col = ct * 16 + l15;
          const float bsv = g_bsp[tile * 128 + col];
#pragma unroll
          for (int r = 0; r < 4; ++r) {
            int row = wv * 32 + rt * 16 + lg * 4 + r;
            int pair = pairBase + row;
            int jj = pair & 255, ii = pair >> 8;
            if (jj > ii) g_xs[(size_t)pair * GG + tile * 128 + col] = f2bf(acc[rt][ct][r] + bsv);
          }
        }
    } else {
      // kterm: sum_h relu(x + bk) * Wl[h]
#pragma unroll
      for (int rt = 0; rt < 2; ++rt) {
#pragma unroll
        for (int r = 0; r < 4; ++r) {
          float s = 0.f;
#pragma unroll
          for (int ct = 0; ct < 8; ++ct) {
            int col = ct * 16 + l15;
            float x = acc[rt][ct][r] + bk[col];
            x = fmaxf(x, 0.f);
            s = fmaf(x, Wl[col], s);
          }
#pragma unroll
          for (int m = 1; m < 16; m <<= 1) s += __shfl_xor(s, m, 64);
          int row = wv * 32 + rt * 16 + lg * 4 + r;
          int pair = pairBase + row;
          int jj = pair & 255, ii = pair >> 8;
          if (l15 == 0 && jj >= ii) g_kterm[pair] = s;
        }
      }
    }
  }
}

// ---------------- masked row softmax -> yes_skip, no_skip ----------------
__global__ __launch_bounds__(256) void k_softmax() {
  const int i = blockIdx.x, j = threadIdx.x;
  __shared__ float sm[NN];
  float x = -1e30f;
  if (j >= i) x = g_kterm[i * NN + j];
  sm[j] = x;
  __syncthreads();
  for (int s = 128; s > 0; s >>= 1) { if (j < s) sm[j] = fmaxf(sm[j], sm[j + s]); __syncthreads(); }
  float mx = sm[0];
  __syncthreads();
  float e = (j >= i) ? __expf(x - mx) : 0.f;
  sm[j] = e;
  __syncthreads();
  for (int s = 128; s > 0; s >>= 1) { if (j < s) sm[j] += sm[j + s]; __syncthreads(); }
  float p = e * frcp(sm[0]);
  g_yesw[i * NN + j] = (j == i) ? 0.f : p;
  if (j == i) g_noskip[i] = p;
}

// ---------------- per-step fused: node LSTM/branch/scatter (blocks 0-255)
//                  + skip LSTM/aggregate (blocks 256+, chunk=16) ----------------
__global__ __launch_bounds__(128) void k_step(const float* __restrict__ Wb,
                                              const float* __restrict__ bb,
                                              const int* __restrict__ tix,
                                              const int* __restrict__ fix) {
  const int t = threadIdx.x;
  if (blockIdx.x < 256) {
    const int i = blockIdx.x;
    __shared__ float hsm[HH];
    __shared__ float red[2][2];
    hsm[t] = g_h[i * HH + t];
    __syncthreads();
    float a0 = g_xg[i * GG + t], a1 = g_xg[i * GG + 128 + t];
    float a2 = g_xg[i * GG + 256 + t], a3 = g_xg[i * GG + 384 + t];
    for (int k = 0; k < HH; ++k) {
      float hv = hsm[k];
      const float4 wa = *(const float4*)&g_pwh[((size_t)k * HH + t) * 4];
      a0 = fmaf(hv, wa.x, a0); a1 = fmaf(hv, wa.y, a1);
      a2 = fmaf(hv, wa.z, a2); a3 = fmaf(hv, wa.w, a3);
    }
    float co = g_c[i * HH + t];
    float c2 = sigm(a1) * co + sigm(a0) * tanhfast(a2);
    float h2 = sigm(a3) * tanhfast(c2);
    float q0 = c2 * Wb[2 * t] + h2 * Wb[2 * (128 + t)];
    float q1 = c2 * Wb[2 * t + 1] + h2 * Wb[2 * (128 + t) + 1];
#pragma unroll
    for (int m = 1; m < 64; m <<= 1) { q0 += __shfl_xor(q0, m, 64); q1 += __shfl_xor(q1, m, 64); }
    if ((t & 63) == 0) { red[t >> 6][0] = q0; red[t >> 6][1] = q1; }
    __syncthreads();
    float l0 = red[0][0] + red[1][0] + bb[0];
    float l1 = red[0][1] + red[1][1] + bb[1];
    float mm = fmaxf(l0, l1);
    float e0 = __expf(l0 - mm), e1 = __expf(l1 - mm);
    float inv = frcp(e0 + e1);
    float ipv = g_ip[i] * g_noskip[i];
    if (ipv != 0.f) {
      float pbt = ipv * e0 * inv, pbf = ipv * e1 * inv;
      int ti = tix[i], fi = fix[i];
      atomicAdd(&g_sc[ti * HH + t], c2 * pbt);
      atomicAdd(&g_sh[ti * HH + t], h2 * pbt);
      atomicAdd(&g_sc[fi * HH + t], c2 * pbf);
      atomicAdd(&g_sh[fi * HH + t], h2 * pbf);
      if (t == 0) { atomicAdd(&g_nip[ti], pbt); atomicAdd(&g_nip[fi], pbf); }
    }
  } else {
    const int idx = blockIdx.x - 256;
    const int j = idx >> 4, chunk = idx & 15;
    const int i0 = chunk * 16;
    if (i0 >= j) return;
    const int iN = (j - i0 < 16) ? (j - i0) : 16;
    __shared__ float wsh[16];
    if (t < 16) wsh[t] = (t < iN) ? g_ip[i0 + t] * g_yesw[(i0 + t) * NN + j] : 0.f;
    __syncthreads();
    float accC = 0.f, accH = 0.f, accW = 0.f;
    for (int ii = 0; ii < iN; ++ii) {
      float wgt = wsh[ii];
      if (wgt == 0.f) continue;
      const int i = i0 + ii;
      const ushort4 gv = *(const ushort4*)&g_xs[((size_t)(i * NN + j) * 128 + t) * 4];
      float4 hw = *(const float4*)&g_hws[((size_t)i * HH + t) * 4];
      float xi = bf2f(gv.x) + hw.x;
      float xf = bf2f(gv.y) + hw.y;
      float xg = bf2f(gv.z) + hw.z;
      float xo = bf2f(gv.w) + hw.w;
      float c2 = sigm(xf) * g_c[i * HH + t] + sigm(xi) * tanhfast(xg);
      float h2 = sigm(xo) * tanhfast(c2);
      accC = fmaf(wgt, c2, accC);
      accH = fmaf(wgt, h2, accH);
      accW += wgt;
    }
    if (accW != 0.f) {
      atomicAdd(&g_sc[j * HH + t], accC);
      atomicAdd(&g_sh[j * HH + t], accH);
      if (t == 0) atomicAdd(&g_nip[j], accW);
    }
  }
}

// ---------------- per-step: finalize carry + compute hws = h@Whs for next step ----------------
__global__ __launch_bounds__(256) void k_finish(const int last) {
  const int j = blockIdx.x, tid = threadIdx.x;
  const int t = tid & 127, half = tid >> 7;
  __shared__ float hsm[HH];
  __shared__ float4 part[2][HH];
  if (half == 0) {
    float nip = g_nip[j];
    float d = frcp(nip + 1e-7f);
    float cv = g_sc[j * HH + t] * d;
    float hv = g_sh[j * HH + t] * d;
    g_c[j * HH + t] = cv;
    g_h[j * HH + t] = hv;
    hsm[t] = hv;
    g_sc[j * HH + t] = 0.f;
    g_sh[j * HH + t] = 0.f;
    if (t == 0) { g_ip[j] = nip; g_nip[j] = 0.f; }
  }
  __syncthreads();
  if (last) return;
  float s0 = 0.f, s1 = 0.f, s2 = 0.f, s3 = 0.f;
  const int k0 = half * 64;
  for (int k = k0; k < k0 + 64; ++k) {
    float hk = hsm[k];
    const float4 w = *(const float4*)&g_pws[((size_t)k * HH + t) * 4];
    s0 = fmaf(hk, w.x, s0); s1 = fmaf(hk, w.y, s1);
    s2 = fmaf(hk, w.z, s2); s3 = fmaf(hk, w.w, s3);
  }
  part[half][t] = make_float4(s0, s1, s2, s3);
  __syncthreads();
  if (half == 0) {
    float4 a = part[0][t], bq = part[1][t];
    *(float4*)&g_hws[((size_t)j * HH + t) * 4] =
        make_float4(a.x + bq.x, a.y + bq.y, a.z + bq.z, a.w + bq.w);
  }
}

// ---------------- output: [c[exit], h[exit]] @ Wd + bd ----------------
__global__ __launch_bounds__(64) void k_out(const float* __restrict__ Wd,
                                            const float* __restrict__ bd,
                                            const int* __restrict__ ei,
                                            float* __restrict__ out) {
  const int v = threadIdx.x;
  const int e = ei[0];
  float s = bd[v];
  for (int h = 0; h < HH; ++h) {
    s = fmaf(g_c[e * HH + h], Wd[h * 64 + v], s);
    s = fmaf(g_h[e * HH + h], Wd[(128 + h) * 64 + v], s);
  }
  out[v] = s;
}

extern "C" void kernel_launch(void* const* d_in, const int* in_sizes, int n_in,
                              void* d_out, int out_size, void* d_ws, size_t ws_size,
                              hipStream_t stream) {
  const float* NE  = (const float*)d_in[0];
  const float* SE  = (const float*)d_in[1];
  const float* Wx  = (const float*)d_in[2];
  const float* Wh  = (const float*)d_in[3];
  const float* b   = (const float*)d_in[4];
  const float* Wxs = (const float*)d_in[5];
  const float* Whs = (const float*)d_in[6];
  const float* bs  = (const float*)d_in[7];
  const float* Wb  = (const float*)d_in[8];
  const float* bb  = (const float*)d_in[9];
  const float* Wk  = (const float*)d_in[10];
  const float* bk  = (const float*)d_in[11];
  // d_in[12] Wq, d_in[13] bq, d_in[15] bl: cancel in row-softmax -> unused
  const float* Wl  = (const float*)d_in[14];
  const float* Wd  = (const float*)d_in[16];
  const float* bd  = (const float*)d_in[17];
  // d_in[18] skip_mask is structurally triu -> computed as (j >= i)
  const int* tix = (const int*)d_in[19];
  const int* fix = (const int*)d_in[20];
  const int* ei  = (const int*)d_in[21];
  float* out = (float*)d_out;

  k_init<<<256, 128, 0, stream>>>();
  k_prep<<<20, 512, 0, stream>>>(Wxs, Wk, bs);
  k_prep2<<<128, 128, 0, stream>>>(Wh, Whs);
  k_xg<<<256, 128, 0, stream>>>(NE, Wx, b);
  k_gemm<<<384, 256, 0, stream>>>(SE, bk, Wl);
  k_softmax<<<256, 256, 0, stream>>>();
  for (int s = 0; s < 4; ++s) {
    k_step<<<256 + 4096, 128, 0, stream>>>(Wb, bb, tix, fix);
    k_finish<<<256, 256, 0, stream>>>(s == 3);
  }
  k_out<<<1, 64, 0, stream>>>(Wd, bd, ei, out);
}

// Round 5
// 156.368 us; speedup vs baseline: 1.8595x; 1.0598x over previous
//
#include <hip/hip_runtime.h>
#include <hip/hip_bf16.h>

constexpr int NN = 256;
constexpr int HH = 128;
constexpr int GG = 512;   // 4H
constexpr int NP = NN * NN;

typedef __attribute__((ext_vector_type(8))) short short8;
typedef __attribute__((ext_vector_type(4))) float f32x4;

// static device scratch
__device__ unsigned short g_xs[(size_t)NP * GG]; // bf16: SE@Wxs+bs, layout [pair][h][gate]
__device__ unsigned short g_wfr[20 * 512 * 8];   // B in MFMA-fragment order: [(tile*4+ks)][ct*64+l][8]
__device__ float g_bsp[GG];                      // bs permuted to col' order
__device__ float g_pwh[HH * HH * 4];             // Wh packed [k][t][gate]
__device__ float g_pws[HH * HH * 4];             // Whs packed [k][t][gate]
__device__ float g_kterm[NP];
__device__ float g_yesw[NP];    // skip_dec, zero diagonal & lower-tri
__device__ float g_noskip[NN];  // diag(skip_dec)
__device__ float g_xg[NN * HH * 4];  // node_emb@Wx + b, packed [i][t][gate]
__device__ float g_xga[NN * HH * 4]; // xg + h@Wh (current step), packed [i][t][gate]
__device__ float g_hws[NN * HH * 4]; // h@Whs, layout [i][t][gate]
__device__ float g_c[NN * HH];
__device__ float g_h[NN * HH];
__device__ float g_sc[NN * HH];
__device__ float g_sh[NN * HH];
__device__ float g_ip[NN];
__device__ float g_nip[NN];

__device__ __forceinline__ unsigned short f2bf(float f) {
  unsigned int u = __float_as_uint(f);
  u = (u + 0x7fffu + ((u >> 16) & 1u)) >> 16;
  return (unsigned short)u;
}
__device__ __forceinline__ float bf2f(unsigned short s) {
  return __uint_as_float(((unsigned int)s) << 16);
}
__device__ __forceinline__ float frcp(float x) {
#if __has_builtin(__builtin_amdgcn_rcpf)
  return __builtin_amdgcn_rcpf(x);
#else
  return 1.0f / x;
#endif
}
__device__ __forceinline__ float sigm(float x) { return frcp(1.f + __expf(-x)); }
__device__ __forceinline__ float tanhfast(float x) { return 1.f - 2.f * frcp(__expf(2.f * x) + 1.f); }

// ---------------- init ----------------
__global__ void k_init() {
  int idx = blockIdx.x * blockDim.x + threadIdx.x; // 32768 threads
  g_sc[idx] = 0.f; g_sh[idx] = 0.f; g_c[idx] = 0.f; g_h[idx] = 0.f;
  *(float4*)&g_hws[(size_t)idx * 4] = make_float4(0.f, 0.f, 0.f, 0.f);
  if (idx < NN) { g_nip[idx] = 0.f; g_ip[idx] = (idx == 0) ? 1.f : 0.f; }
}

// ---------------- weight pack: B in MFMA fragment order ----------------
__global__ __launch_bounds__(512) void k_prep(const float* __restrict__ Wxs,
                                              const float* __restrict__ Wk,
                                              const float* __restrict__ bs) {
  const int bidx = blockIdx.x;   // 0..19 = tile*4+ks
  const int tile = bidx >> 2, ks = bidx & 3;
  const int s = threadIdx.x;     // 0..511
  const int ct = s >> 6, l = s & 63;
  const int c = ct * 16 + (l & 15);
  const int kbase = ks * 32 + (l >> 4) * 8;
  int src = 0;
  if (tile < 4) src = (c & 3) * 128 + tile * 32 + (c >> 2);
  unsigned short* dst = &g_wfr[((size_t)bidx * 512 + s) * 8];
#pragma unroll
  for (int e = 0; e < 8; ++e) {
    int k = kbase + e;
    float v = (tile < 4) ? Wxs[k * GG + src] : Wk[k * HH + c];
    dst[e] = f2bf(v);
  }
  if (tile < 4 && ks == 0 && (l >> 4) == 0) g_bsp[tile * 128 + c] = bs[src];
}

// ---------------- pack Wh/Whs as [k][t][gate] float4 ----------------
__global__ __launch_bounds__(128) void k_prep2(const float* __restrict__ Wh,
                                               const float* __restrict__ Whs) {
  const int k = blockIdx.x, t = threadIdx.x;
  float4 a = make_float4(Wh[k * GG + t], Wh[k * GG + 128 + t], Wh[k * GG + 256 + t], Wh[k * GG + 384 + t]);
  float4 s = make_float4(Whs[k * GG + t], Whs[k * GG + 128 + t], Whs[k * GG + 256 + t], Whs[k * GG + 384 + t]);
  *(float4*)&g_pwh[((size_t)k * HH + t) * 4] = a;
  *(float4*)&g_pws[((size_t)k * HH + t) * 4] = s;
}

// ---------------- xg = node_emb @ Wx + b, packed [i][t][gate] ----------------
__global__ __launch_bounds__(128) void k_xg(const float* __restrict__ NE,
                                            const float* __restrict__ Wx,
                                            const float* __restrict__ b) {
  const int i = blockIdx.x, t = threadIdx.x;
  __shared__ float ne[HH];
  ne[t] = NE[i * HH + t];
  __syncthreads();
  float a0 = b[t], a1 = b[128 + t], a2 = b[256 + t], a3 = b[384 + t];
  for (int k = 0; k < HH; ++k) {
    float x = ne[k];
    a0 = fmaf(x, Wx[k * GG + t], a0);
    a1 = fmaf(x, Wx[k * GG + 128 + t], a1);
    a2 = fmaf(x, Wx[k * GG + 256 + t], a2);
    a3 = fmaf(x, Wx[k * GG + 384 + t], a3);
  }
  float4 v = make_float4(a0, a1, a2, a3);
  *(float4*)&g_xg[((size_t)i * HH + t) * 4] = v;
  *(float4*)&g_xga[((size_t)i * HH + t) * 4] = v;  // step 0: h=0 -> xga = xg
}

__device__ __forceinline__ void loadB(short8* dst, int tile, int ks, int l) {
  const unsigned short* wf = &g_wfr[((size_t)(tile * 4 + ks)) * 4096 + l * 8];
#pragma unroll
  for (int ct = 0; ct < 8; ++ct) dst[ct] = *(const short8*)(wf + ct * 512);
}

// ---------------- fused GEMM: xs_gates (y=0..3, permuted cols) + kterm (y=4) ----------------
// grid (384 pair-tiles, 5 col-tiles); A staged per block; B from global in fragment order.
__global__ __launch_bounds__(256) void k_gemm(const float* __restrict__ SE,
                                              const float* __restrict__ bk,
                                              const float* __restrict__ Wl) {
  __shared__ __align__(16) char lds[32768];
  const int bid = blockIdx.x;
  const int tile = blockIdx.y;
  const int pb = (bid < 128) ? (bid * 2) : ((bid - 128) * 2 + 1);
  const int pairBase = pb * 128;
  const int tid = threadIdx.x;

  // A: [row][k] f32->bf16, swizzled (byte ^= (row&7)<<4)
  for (int cc = tid; cc < 2048; cc += 256) {
    int row = cc >> 4, kc = cc & 15;
    const float* src = SE + (size_t)(pairBase + row) * HH + kc * 8;
    float4 f0 = *(const float4*)(src);
    float4 f1 = *(const float4*)(src + 4);
    short8 v;
    v[0] = (short)f2bf(f0.x); v[1] = (short)f2bf(f0.y); v[2] = (short)f2bf(f0.z); v[3] = (short)f2bf(f0.w);
    v[4] = (short)f2bf(f1.x); v[5] = (short)f2bf(f1.y); v[6] = (short)f2bf(f1.z); v[7] = (short)f2bf(f1.w);
    *(short8*)(lds + row * 256 + ((kc * 16) ^ ((row & 7) << 4))) = v;
  }
  __syncthreads();

  const int wv = tid >> 6;
  const int l = tid & 63;
  const int l15 = l & 15, lg = l >> 4;

  f32x4 acc[2][8];
#pragma unroll
  for (int rt = 0; rt < 2; ++rt)
#pragma unroll
    for (int ct = 0; ct < 8; ++ct) acc[rt][ct] = (f32x4){0.f, 0.f, 0.f, 0.f};

  short8 bA[8], bB[8];
  loadB(bA, tile, 0, l);
#pragma unroll
  for (int ks = 0; ks < 4; ks += 2) {
    loadB(bB, tile, ks + 1, l);
    {
      const int kb = ks * 64 + lg * 16;
      short8 a[2];
#pragma unroll
      for (int rt = 0; rt < 2; ++rt) {
        int row = wv * 32 + rt * 16 + l15;
        a[rt] = *(const short8*)(lds + row * 256 + (kb ^ ((row & 7) << 4)));
      }
#pragma unroll
      for (int rt = 0; rt < 2; ++rt)
#pragma unroll
        for (int ct = 0; ct < 8; ++ct)
          acc[rt][ct] = __builtin_amdgcn_mfma_f32_16x16x32_bf16(a[rt], bA[ct], acc[rt][ct], 0, 0, 0);
    }
    if (ks + 2 < 4) loadB(bA, tile, ks + 2, l);
    {
      const int kb = (ks + 1) * 64 + lg * 16;
      short8 a[2];
#pragma unroll
      for (int rt = 0; rt < 2; ++rt) {
        int row = wv * 32 + rt * 16 + l15;
        a[rt] = *(const short8*)(lds + row * 256 + (kb ^ ((row & 7) << 4)));
      }
#pragma unroll
      for (int rt = 0; rt < 2; ++rt)
#pragma unroll
        for (int ct = 0; ct < 8; ++ct)
          acc[rt][ct] = __builtin_amdgcn_mfma_f32_16x16x32_bf16(a[rt], bB[ct], acc[rt][ct], 0, 0, 0);
    }
  }

  if (tile < 4) {
    // contiguous stores: g_xs[pair*512 + tile*128 + col] (col' = h*4+g layout)
#pragma unroll
    for (int rt = 0; rt < 2; ++rt)
#pragma unroll
      for (int ct = 0; ct < 8; ++ct) {
        const int col = ct * 16 + l15;
        const float bsv = g_bsp[tile * 128 + col];
#pragma unroll
        for (int r = 0; r < 4; ++r) {
          int row = wv * 32 + rt * 16 + lg * 4 + r;
          int pair = pairBase + row;
          int jj = pair & 255, ii = pair >> 8;
          if (jj > ii) g_xs[(size_t)pair * GG + tile * 128 + col] = f2bf(acc[rt][ct][r] + bsv);
        }
      }
  } else {
    // kterm: sum_h relu(x + bk) * Wl[h]
#pragma unroll
    for (int rt = 0; rt < 2; ++rt) {
#pragma unroll
      for (int r = 0; r < 4; ++r) {
        float s = 0.f;
#pragma unroll
        for (int ct = 0; ct < 8; ++ct) {
          int col = ct * 16 + l15;
          float x = acc[rt][ct][r] + bk[col];
          x = fmaxf(x, 0.f);
          s = fmaf(x, Wl[col], s);
        }
#pragma unroll
        for (int m = 1; m < 16; m <<= 1) s += __shfl_xor(s, m, 64);
        int row = wv * 32 + rt * 16 + lg * 4 + r;
        int pair = pairBase + row;
        int jj = pair & 255, ii = pair >> 8;
        if (l15 == 0 && jj >= ii) g_kterm[pair] = s;
      }
    }
  }
}

// ---------------- masked row softmax -> yes_skip, no_skip ----------------
__global__ __launch_bounds__(256) void k_softmax() {
  const int i = blockIdx.x, j = threadIdx.x;
  __shared__ float sm[NN];
  float x = -1e30f;
  if (j >= i) x = g_kterm[i * NN + j];
  sm[j] = x;
  __syncthreads();
  for (int s = 128; s > 0; s >>= 1) { if (j < s) sm[j] = fmaxf(sm[j], sm[j + s]); __syncthreads(); }
  float mx = sm[0];
  __syncthreads();
  float e = (j >= i) ? __expf(x - mx) : 0.f;
  sm[j] = e;
  __syncthreads();
  for (int s = 128; s > 0; s >>= 1) { if (j < s) sm[j] += sm[j + s]; __syncthreads(); }
  float p = e * frcp(sm[0]);
  g_yesw[i * NN + j] = (j == i) ? 0.f : p;
  if (j == i) g_noskip[i] = p;
}

// ---------------- per-step fused: node gate-math/branch/scatter (blocks 0-255)
//                  + skip LSTM/aggregate (blocks 256+, chunk=16) ----------------
__global__ __launch_bounds__(128) void k_step(const float* __restrict__ Wb,
                                              const float* __restrict__ bb,
                                              const int* __restrict__ tix,
                                              const int* __restrict__ fix) {
  const int t = threadIdx.x;
  if (blockIdx.x < 256) {
    const int i = blockIdx.x;
    __shared__ float red[2][2];
    const float4 a = *(const float4*)&g_xga[((size_t)i * HH + t) * 4];
    float co = g_c[i * HH + t];
    float c2 = sigm(a.y) * co + sigm(a.x) * tanhfast(a.z);
    float h2 = sigm(a.w) * tanhfast(c2);
    float q0 = c2 * Wb[2 * t] + h2 * Wb[2 * (128 + t)];
    float q1 = c2 * Wb[2 * t + 1] + h2 * Wb[2 * (128 + t) + 1];
#pragma unroll
    for (int m = 1; m < 64; m <<= 1) { q0 += __shfl_xor(q0, m, 64); q1 += __shfl_xor(q1, m, 64); }
    if ((t & 63) == 0) { red[t >> 6][0] = q0; red[t >> 6][1] = q1; }
    __syncthreads();
    float l0 = red[0][0] + red[1][0] + bb[0];
    float l1 = red[0][1] + red[1][1] + bb[1];
    float mm = fmaxf(l0, l1);
    float e0 = __expf(l0 - mm), e1 = __expf(l1 - mm);
    float inv = frcp(e0 + e1);
    float ipv = g_ip[i] * g_noskip[i];
    if (ipv != 0.f) {
      float pbt = ipv * e0 * inv, pbf = ipv * e1 * inv;
      int ti = tix[i], fi = fix[i];
      atomicAdd(&g_sc[ti * HH + t], c2 * pbt);
      atomicAdd(&g_sh[ti * HH + t], h2 * pbt);
      atomicAdd(&g_sc[fi * HH + t], c2 * pbf);
      atomicAdd(&g_sh[fi * HH + t], h2 * pbf);
      if (t == 0) { atomicAdd(&g_nip[ti], pbt); atomicAdd(&g_nip[fi], pbf); }
    }
  } else {
    const int idx = blockIdx.x - 256;
    const int j = idx >> 4, chunk = idx & 15;
    const int i0 = chunk * 16;
    if (i0 >= j) return;
    const int iN = (j - i0 < 16) ? (j - i0) : 16;
    __shared__ float wsh[16];
    if (t < 16) wsh[t] = (t < iN) ? g_ip[i0 + t] * g_yesw[(i0 + t) * NN + j] : 0.f;
    __syncthreads();
    float accC = 0.f, accH = 0.f, accW = 0.f;
    for (int ii = 0; ii < iN; ++ii) {
      float wgt = wsh[ii];
      if (wgt == 0.f) continue;
      const int i = i0 + ii;
      const ushort4 gv = *(const ushort4*)&g_xs[((size_t)(i * NN + j) * 128 + t) * 4];
      float4 hw = *(const float4*)&g_hws[((size_t)i * HH + t) * 4];
      float xi = bf2f(gv.x) + hw.x;
      float xf = bf2f(gv.y) + hw.y;
      float xg = bf2f(gv.z) + hw.z;
      float xo = bf2f(gv.w) + hw.w;
      float c2 = sigm(xf) * g_c[i * HH + t] + sigm(xi) * tanhfast(xg);
      float h2 = sigm(xo) * tanhfast(c2);
      accC = fmaf(wgt, c2, accC);
      accH = fmaf(wgt, h2, accH);
      accW += wgt;
    }
    if (accW != 0.f) {
      atomicAdd(&g_sc[j * HH + t], accC);
      atomicAdd(&g_sh[j * HH + t], accH);
      if (t == 0) atomicAdd(&g_nip[j], accW);
    }
  }
}

// ---------------- per-step: finalize carry + xga = xg + h@Wh + hws = h@Whs ----------------
// 512 threads: sel = tid>>7: {0,1} -> xga (k halves), {2,3} -> hws (k halves)
__global__ __launch_bounds__(512) void k_finish(const int last) {
  const int j = blockIdx.x, tid = threadIdx.x;
  const int t = tid & 127, sel = tid >> 7;
  __shared__ float hsm[HH];
  __shared__ float4 part[4][HH];
  if (sel == 0) {
    float nip = g_nip[j];
    float d = frcp(nip + 1e-7f);
    float cv = g_sc[j * HH + t] * d;
    float hv = g_sh[j * HH + t] * d;
    g_c[j * HH + t] = cv;
    g_h[j * HH + t] = hv;
    hsm[t] = hv;
    g_sc[j * HH + t] = 0.f;
    g_sh[j * HH + t] = 0.f;
    if (t == 0) { g_ip[j] = nip; g_nip[j] = 0.f; }
  }
  __syncthreads();
  if (last) return;
  const float* __restrict__ W = (sel >> 1) ? g_pws : g_pwh;
  const int k0 = (sel & 1) * 64;
  float s0 = 0.f, s1 = 0.f, s2 = 0.f, s3 = 0.f;
#pragma unroll 8
  for (int k = k0; k < k0 + 64; ++k) {
    float hk = hsm[k];
    const float4 w = *(const float4*)&W[((size_t)k * HH + t) * 4];
    s0 = fmaf(hk, w.x, s0); s1 = fmaf(hk, w.y, s1);
    s2 = fmaf(hk, w.z, s2); s3 = fmaf(hk, w.w, s3);
  }
  part[sel][t] = make_float4(s0, s1, s2, s3);
  __syncthreads();
  if (sel == 0) {
    float4 p0 = part[0][t], p1 = part[1][t];
    float4 xg = *(const float4*)&g_xg[((size_t)j * HH + t) * 4];
    *(float4*)&g_xga[((size_t)j * HH + t) * 4] =
        make_float4(xg.x + p0.x + p1.x, xg.y + p0.y + p1.y,
                    xg.z + p0.z + p1.z, xg.w + p0.w + p1.w);
  } else if (sel == 2) {
    float4 p2 = part[2][t], p3 = part[3][t];
    *(float4*)&g_hws[((size_t)j * HH + t) * 4] =
        make_float4(p2.x + p3.x, p2.y + p3.y, p2.z + p3.z, p2.w + p3.w);
  }
}

// ---------------- output: [c[exit], h[exit]] @ Wd + bd ----------------
__global__ __launch_bounds__(64) void k_out(const float* __restrict__ Wd,
                                            const float* __restrict__ bd,
                                            const int* __restrict__ ei,
                                            float* __restrict__ out) {
  const int v = threadIdx.x;
  const int e = ei[0];
  float s = bd[v];
  for (int h = 0; h < HH; ++h) {
    s = fmaf(g_c[e * HH + h], Wd[h * 64 + v], s);
    s = fmaf(g_h[e * HH + h], Wd[(128 + h) * 64 + v], s);
  }
  out[v] = s;
}

extern "C" void kernel_launch(void* const* d_in, const int* in_sizes, int n_in,
                              void* d_out, int out_size, void* d_ws, size_t ws_size,
                              hipStream_t stream) {
  const float* NE  = (const float*)d_in[0];
  const float* SE  = (const float*)d_in[1];
  const float* Wx  = (const float*)d_in[2];
  const float* Wh  = (const float*)d_in[3];
  const float* b   = (const float*)d_in[4];
  const float* Wxs = (const float*)d_in[5];
  const float* Whs = (const float*)d_in[6];
  const float* bs  = (const float*)d_in[7];
  const float* Wb  = (const float*)d_in[8];
  const float* bb  = (const float*)d_in[9];
  const float* Wk  = (const float*)d_in[10];
  const float* bk  = (const float*)d_in[11];
  // d_in[12] Wq, d_in[13] bq, d_in[15] bl: cancel in row-softmax -> unused
  const float* Wl  = (const float*)d_in[14];
  const float* Wd  = (const float*)d_in[16];
  const float* bd  = (const float*)d_in[17];
  // d_in[18] skip_mask is structurally triu -> computed as (j >= i)
  const int* tix = (const int*)d_in[19];
  const int* fix = (const int*)d_in[20];
  const int* ei  = (const int*)d_in[21];
  float* out = (float*)d_out;

  k_init<<<256, 128, 0, stream>>>();
  k_prep<<<20, 512, 0, stream>>>(Wxs, Wk, bs);
  k_prep2<<<128, 128, 0, stream>>>(Wh, Whs);
  k_xg<<<256, 128, 0, stream>>>(NE, Wx, b);
  k_gemm<<<dim3(384, 5), 256, 0, stream>>>(SE, bk, Wl);
  k_softmax<<<256, 256, 0, stream>>>();
  for (int s = 0; s < 4; ++s) {
    k_step<<<256 + 4096, 128, 0, stream>>>(Wb, bb, tix, fix);
    k_finish<<<256, 512, 0, stream>>>(s == 3);
  }
  k_out<<<1, 64, 0, stream>>>(Wd, bd, ei, out);
}